// Round 4
// baseline (500.669 us; speedup 1.0000x reference)
//
#include <hip/hip_runtime.h>
#include <hip/hip_bf16.h>

typedef unsigned short u16;

#define Bb  128
#define Ss  200
#define Tt  199   // S-1
#define Dd  128
#define Kk  4
#define NQq 10000
#define NCc 500

__device__ inline float bf2f(u16 u) {
    union { unsigned int i; float f; } x;
    x.i = ((unsigned int)u) << 16;
    return x.f;
}

// mode m: 1 = buffers hold fp32, 0 = buffers hold bf16
__device__ inline float ldf(const void* p, int i, int m) {
    if (m) return ((const float*)p)[i];
    return bf2f(((const u16*)p)[i]);
}

__device__ inline void stf(void* p, int i, int m, float v) {
    if (m) ((float*)p)[i] = v;
    else ((__hip_bfloat16*)p)[i] = __float2bfloat16(v);
}

__device__ inline int clampi(int v, int lo, int hi) {
    return v < lo ? lo : (v > hi ? hi : v);
}

__device__ inline float wave_red(float v) {
#pragma unroll
    for (int m = 32; m >= 1; m >>= 1) v += __shfl_xor(v, m);
    return v;
}

// ---------------- Pd: detect input float storage (fp32 vs bf16) ------------
__global__ __launch_bounds__(256) void p_detect(const void* Eq, int* flag) {
    const int tid = threadIdx.x;
    const u16* q = (const u16*)Eq;
    float mx = 0.f;
    for (int i = tid; i < 4096; i += 256) {
        float a = fabsf(bf2f(q[i]));
        if (!(a == a)) a = 3.0e38f;  // NaN -> huge
        mx = fmaxf(mx, a);
    }
#pragma unroll
    for (int s = 32; s >= 1; s >>= 1) mx = fmaxf(mx, __shfl_xor(mx, s));
    __shared__ float sm[4];
    if ((tid & 63) == 0) sm[tid >> 6] = mx;
    __syncthreads();
    if (tid == 0) {
        float m2 = fmaxf(fmaxf(sm[0], sm[1]), fmaxf(sm[2], sm[3]));
        flag[0] = (m2 > 1.0e6f) ? 1 : 0;   // bf16 data: ~0.5; fp32-as-bf16: ~1e38
    }
}

// ---------------- P0: cs2 (colsum of W_fuse bottom half) + concept norms ----
__global__ __launch_bounds__(128) void p0_prep(const void* Wf, const void* Ec,
                                               const int* mode,
                                               float* cs2, float* cnorm) {
    const int m = mode[0];
    const int tid = threadIdx.x;
    if (blockIdx.x == 0) {
        float s = 0.f;
        for (int r = 0; r < 128; ++r) s += ldf(Wf, (128 + r) * 128 + tid, m);
        cs2[tid] = s;
    } else {
        const int c = blockIdx.x - 1;  // 0..499
        float v = ldf(Ec, c * 128 + tid, m);
        float s = wave_red(v * v);
        __shared__ float tmp[2];
        if ((tid & 63) == 0) tmp[tid >> 6] = s;
        __syncthreads();
        if (tid == 0) cnorm[c] = fmaxf(sqrtf(tmp[0] + tmp[1]), 1e-8f);
    }
}

// ---------------- P1: folded weight prep -----------------------------------
// Bab rows: [0:128)=Wf_top@WA1, [128:256)=WA2, [256:384)=WA3
// Bfg rows: [0:128)=Wf_top@WF3, [128:256)=WF2
__global__ __launch_bounds__(128) void p1_weights(
    const void* Wf, const void* Wa, const void* Wg,
    const void* bfu, const void* ba, const void* bg,
    const int* mode, const float* cs2, float* Bab, float* Bfg,
    float* vA0, float* vA1, float* vF0, float* vF1) {
    const int m = mode[0];
    const int bi = blockIdx.x, tid = threadIdx.x;
    if (bi < 128) {
        float acc = 0.f;
        for (int j = 0; j < 128; ++j)
            acc += ldf(Wf, bi * 128 + j, m) * ldf(Wa, j * 128 + tid, m);
        Bab[bi * 128 + tid] = acc;
    } else if (bi < 256) {
        const int i = bi - 128;
        float acc = 0.f;
        for (int j = 0; j < 128; ++j)
            acc += ldf(Wf, i * 128 + j, m) * ldf(Wg, (256 + j) * 128 + tid, m);
        Bfg[i * 128 + tid] = acc;
    } else if (bi < 512) {
        const int r = bi - 256 + 128;  // 128..383
        Bab[r * 128 + tid] = ldf(Wa, r * 128 + tid, m);
    } else if (bi < 640) {
        const int r = bi - 512 + 128;  // 128..255
        Bfg[r * 128 + tid] = ldf(Wg, r * 128 + tid, m);
    } else if (bi == 640) {
        float a0 = 0.f, a1 = 0.f;
        for (int j = 0; j < 128; ++j) {
            float wv = ldf(Wa, j * 128 + tid, m);
            a0 += ldf(bfu, j, m) * wv;
            a1 += cs2[j] * wv;
        }
        vA0[tid] = a0 + ldf(ba, tid, m);
        vA1[tid] = a1;
    } else {
        float a0 = 0.f, a1 = 0.f;
        for (int j = 0; j < 128; ++j) {
            float wv = ldf(Wg, (256 + j) * 128 + tid, m);
            a0 += ldf(bfu, j, m) * wv;
            a1 += cs2[j] * wv;
        }
        vF0[tid] = a0 + ldf(bg, tid, m);
        vF1[tid] = a1;
    }
}

// ---------------- P2: per-(t,b) gathers + qdiff (4 rows per block) ---------
__global__ __launch_bounds__(256) void p2_rows(
    const int* q_seq, const int* ha_seq, const int* it_seq, const int* ut_seq,
    const int* q2c, const int* q2cm,
    const void* Eq, const void* Eqd, const void* Ec,
    const int* mode, const float* cnorm,
    float* scal, int* cidx, int* eidx) {
    const int m = mode[0];
    const int wv = threadIdx.x >> 6, lane = threadIdx.x & 63;
    const int r = blockIdx.x * 4 + wv;  // r = t*128 + b; grid*4 == Tt*Bb exactly
    const int t = r >> 7, b = r & 127;
    const int qt  = q_seq[b * Ss + t];
    const int qt1 = q_seq[b * Ss + t + 1];
    const float qa = ldf(Eq, qt * 128 + lane, m);
    const float qb = ldf(Eq, qt * 128 + 64 + lane, m);
    const float nqc = fmaxf(sqrtf(wave_red(qa * qa + qb * qb)), 1e-8f);
    const int4 cc = ((const int4*)q2c)[qt];
    const int4 mm = ((const int4*)q2cm)[qt];
    const int cks[4] = {clampi(cc.x, 0, NCc - 1), clampi(cc.y, 0, NCc - 1),
                        clampi(cc.z, 0, NCc - 1), clampi(cc.w, 0, NCc - 1)};
    const int ms[4]  = {mm.x, mm.y, mm.z, mm.w};
    float qs = 0.f;
#pragma unroll
    for (int k = 0; k < 4; ++k) {
        const int ck = cks[k];
        float dot = wave_red(qa * ldf(Ec, ck * 128 + lane, m) +
                             qb * ldf(Ec, ck * 128 + 64 + lane, m));
        float cosv = dot / (nqc * cnorm[ck]);
        qs += (float)ms[k] * (0.5f * cosv + 0.5f);
    }
    if (lane == 0) {
        const float qd1 = 10.f / (1.f + __expf(-ldf(Eqd, qt1, m)));
        float4 s0 = make_float4(qd1, qs, (float)ms[0], (float)ms[1]);
        float4 s1 = make_float4((float)ms[2], (float)ms[3], 0.f, 0.f);
        ((float4*)scal)[r * 2]     = s0;
        ((float4*)scal)[r * 2 + 1] = s1;
        ((int4*)cidx)[r] = ((const int4*)q2c)[qt1];
        int4 e;
        e.x = qt;
        e.y = ut_seq[b * Ss + t];
        e.z = ha_seq[b * Ss + t];
        e.w = it_seq[b * Ss + t];
        ((int4*)eidx)[r] = e;
    }
}

// ---------------- P3: GEMM  rows x {K=384 -> absorb | K=256 -> pre_forget} --
__global__ __launch_bounds__(256) void p3_gemm(
    const void* Eq, const void* Eut, const void* Eha, const void* Eit,
    const int* eidx, const int* c_seq, const int* mode,
    const float* Bab, const float* Bfg,
    const float* vA0, const float* vA1, const float* vF0, const float* vF1,
    float* absorb, float* pref) {
    __shared__ float At[64][36];
    __shared__ float Bt[32][128];
    __shared__ int eis[64][4];
    __shared__ float cfs[64];
    const int m = mode[0];
    const int tid = threadIdx.x;
    const int r0 = blockIdx.x * 64;
    const int by = blockIdx.y;
    if (tid < 64) {
        const int r = r0 + tid;
        int4 e = ((const int4*)eidx)[r];
        eis[tid][0] = clampi(e.x, 0, NQq - 1);
        eis[tid][1] = clampi(e.y, 0, 99);
        eis[tid][2] = clampi(e.z, 0, 11);
        eis[tid][3] = clampi(e.w, 0, 99);
        cfs[tid] = (float)c_seq[(r & 127) * Ss + (r >> 7)];
    }
    __syncthreads();
    float acc[4][8];
#pragma unroll
    for (int j = 0; j < 4; ++j)
#pragma unroll
        for (int i = 0; i < 8; ++i) acc[j][i] = 0.f;
    const float* Bm = by ? Bfg : Bab;
    const int ng = by ? 2 : 3;
    const int tx = tid & 15, ty = tid >> 4;
    for (int g = 0; g < ng; ++g) {
        const void* tab;
        int comp;
        if (by == 0) { tab = (g == 0) ? Eq : ((g == 1) ? Eut : Eha); comp = g; }
        else         { tab = (g == 0) ? Eq : Eit; comp = (g == 0) ? 0 : 3; }
        for (int ks = 0; ks < 4; ++ks) {
            {   // A tile: 64 rows x 32 k
                const int row = tid >> 2, seg = tid & 3;
                const int ei = eis[row][comp] * 128 + ks * 32 + seg * 8;
                float* dst = &At[row][seg * 8];
                if (m) {
                    const float4* src = (const float4*)((const float*)tab + ei);
                    float4 v0 = src[0], v1 = src[1];
                    dst[0] = v0.x; dst[1] = v0.y; dst[2] = v0.z; dst[3] = v0.w;
                    dst[4] = v1.x; dst[5] = v1.y; dst[6] = v1.z; dst[7] = v1.w;
                } else {
                    uint4 v = *(const uint4*)((const u16*)tab + ei);
                    dst[0] = bf2f((u16)(v.x & 0xffff)); dst[1] = bf2f((u16)(v.x >> 16));
                    dst[2] = bf2f((u16)(v.y & 0xffff)); dst[3] = bf2f((u16)(v.y >> 16));
                    dst[4] = bf2f((u16)(v.z & 0xffff)); dst[5] = bf2f((u16)(v.z >> 16));
                    dst[6] = bf2f((u16)(v.w & 0xffff)); dst[7] = bf2f((u16)(v.w >> 16));
                }
            }
            {   // B tile: 32 x 128
                const float4* Bm4 = (const float4*)(Bm + (g * 128 + ks * 32) * 128);
                float4* Bt4 = (float4*)&Bt[0][0];
#pragma unroll
                for (int k = 0; k < 4; ++k) Bt4[tid + k * 256] = Bm4[tid + k * 256];
            }
            __syncthreads();
#pragma unroll
            for (int kk = 0; kk < 32; kk += 4) {
                float a_[4][4];
                *(float4*)&a_[0][0] = *(const float4*)&At[ty * 4 + 0][kk];
                *(float4*)&a_[1][0] = *(const float4*)&At[ty * 4 + 1][kk];
                *(float4*)&a_[2][0] = *(const float4*)&At[ty * 4 + 2][kk];
                *(float4*)&a_[3][0] = *(const float4*)&At[ty * 4 + 3][kk];
#pragma unroll
                for (int q = 0; q < 4; ++q) {
                    float4 b0 = *(const float4*)&Bt[kk + q][tx * 8];
                    float4 b1 = *(const float4*)&Bt[kk + q][tx * 8 + 4];
#pragma unroll
                    for (int j = 0; j < 4; ++j) {
                        const float av = a_[j][q];
                        acc[j][0] += av * b0.x; acc[j][1] += av * b0.y;
                        acc[j][2] += av * b0.z; acc[j][3] += av * b0.w;
                        acc[j][4] += av * b1.x; acc[j][5] += av * b1.y;
                        acc[j][6] += av * b1.z; acc[j][7] += av * b1.w;
                    }
                }
            }
            __syncthreads();
        }
    }
    const float* v0 = by ? vF0 : vA0;
    const float* v1 = by ? vF1 : vA1;
    float* outbase = by ? pref : absorb;
#pragma unroll
    for (int j = 0; j < 4; ++j) {
        const int row = ty * 4 + j;
        const int r = r0 + row;
        const float cf = cfs[row];
        float* op = outbase + r * 128 + tx * 8;
#pragma unroll
        for (int i = 0; i < 8; ++i) {
            const int dd = tx * 8 + i;
            op[i] = acc[j][i] + v0[dd] + cf * v1[dd];
        }
    }
}

// ---------------- P4: sequential scan, pipelined, 1 barrier/step -----------
// depth-2 prefetch of absorb/pref (HBM ~900cyc), depth-1 of Ec/scal/cnorm (L2)
__global__ __launch_bounds__(256) void p4_scan(
    const void* Wg, const void* L0,
    const float* absorb, const float* pref,
    const float* scal, const int* cidx, const float* cnorm,
    const void* Ec, const int* mode, void* out) {
    const int m = mode[0];
    const int b = blockIdx.x;
    const int tid = threadIdx.x;
    const int d = tid >> 1, half = tid & 1;
    __shared__ float lp[2][128];
    __shared__ float red[2][4][8];
    float w[64];
#pragma unroll
    for (int i = 0; i < 64; ++i)
        w[i] = ldf(Wg, (half * 64 + i) * 128 + d, m);   // WF1[i_global][d]
    float lc = ldf(L0, b * 128 + d, m);
    if (half == 0) lp[0][d] = lc;

    // ---- preload t=0 state ----
    const int4* cidx4 = (const int4*)cidx;
    const float4* scal4 = (const float4*)scal;
    float ab_c = absorb[b * 128 + d];           // r = 0*128+b
    float pf_c = pref[b * 128 + d];
    int4 ci0 = cidx4[b];
    {
        const int c0 = clampi(ci0.x, 0, NCc - 1), c1 = clampi(ci0.y, 0, NCc - 1);
        const int c2 = clampi(ci0.z, 0, NCc - 1), c3 = clampi(ci0.w, 0, NCc - 1);
        ci0.x = c0; ci0.y = c1; ci0.z = c2; ci0.w = c3;
    }
    float cpa_c = ldf(Ec, (half ? ci0.z : ci0.x) * 128 + d, m);
    float cpb_c = ldf(Ec, (half ? ci0.w : ci0.y) * 128 + d, m);
    float4 s0_c = make_float4(0.f, 0.f, 0.f, 0.f), s1_c = s0_c;
    float n0_c = 1.f, n1_c = 1.f, n2_c = 1.f, n3_c = 1.f;
    if (tid == 0) {
        s0_c = scal4[b * 2]; s1_c = scal4[b * 2 + 1];
        n0_c = cnorm[ci0.x]; n1_c = cnorm[ci0.y];
        n2_c = cnorm[ci0.z]; n3_c = cnorm[ci0.w];
    }
    // depth-2 head start for absorb/pref (t=1)
    const int r1h = ((1 < Tt) ? 1 : 0) * 128 + b;
    float ab_n = absorb[r1h * 128 + d];
    float pf_n = pref[r1h * 128 + d];
    int4 ci1 = cidx4[r1h];   // indices for t=1
    __syncthreads();

    for (int t = 0; t < Tt; ++t) {
        const int cur = t & 1, nx = cur ^ 1;
        // ---- prefetch stage ----
        const int t2 = (t + 2 < Tt) ? t + 2 : Tt - 1;
        const float ab_n2 = absorb[(t2 * 128 + b) * 128 + d];
        const float pf_n2 = pref[(t2 * 128 + b) * 128 + d];
        const int4 ci2 = cidx4[t2 * 128 + b];
        const int c0n = clampi(ci1.x, 0, NCc - 1), c1n = clampi(ci1.y, 0, NCc - 1);
        const int c2n = clampi(ci1.z, 0, NCc - 1), c3n = clampi(ci1.w, 0, NCc - 1);
        const float cpa_n = ldf(Ec, (half ? c2n : c0n) * 128 + d, m);
        const float cpb_n = ldf(Ec, (half ? c3n : c1n) * 128 + d, m);
        float4 s0_n = s0_c, s1_n = s1_c;
        float n0_n = n0_c, n1_n = n1_c, n2_n = n2_c, n3_n = n3_c;
        if (tid == 0) {
            const int rr1 = ((t + 1 < Tt) ? t + 1 : Tt - 1) * 128 + b;
            s0_n = scal4[rr1 * 2]; s1_n = scal4[rr1 * 2 + 1];
            n0_n = cnorm[c0n]; n1_n = cnorm[c1n];
            n2_n = cnorm[c2n]; n3_n = cnorm[c3n];
        }
        // ---- matvec lp @ WF1 (this thread's 64-i half) ----
        const float* lpc = &lp[cur][half * 64];
        float fs = 0.f;
#pragma unroll
        for (int i = 0; i < 64; i += 4) {
            float4 v = *(const float4*)(lpc + i);
            fs += w[i] * v.x + w[i + 1] * v.y + w[i + 2] * v.z + w[i + 3] * v.w;
        }
        fs += __shfl_xor(fs, 1);  // combine halves of the (d) pair
        const float forget = 1.f / (1.f + __expf(-(fs + pf_c)));
        lc = lc * forget + ab_c;
        // cosine partials: even lanes (lc^2, lc*cp0, lc*cp1); odd (0, lc*cp2, lc*cp3)
        float a0 = half ? 0.f : lc * lc;
        float a1 = lc * cpa_c, a2 = lc * cpb_c;
#pragma unroll
        for (int mm = 2; mm <= 32; mm <<= 1) {
            a0 += __shfl_xor(a0, mm); a1 += __shfl_xor(a1, mm); a2 += __shfl_xor(a2, mm);
        }
        if (half == 0) lp[nx][d] = lc;
        const int wvi = tid >> 6, lane = tid & 63;
        if (lane == 0)      { red[cur][wvi][0] = a0; red[cur][wvi][1] = a1; red[cur][wvi][2] = a2; }
        else if (lane == 1) { red[cur][wvi][3] = a1; red[cur][wvi][4] = a2; }
        __syncthreads();   // lp[nx] + red[cur] published
        if (tid == 0) {    // epilogue overlaps other threads' next-step work
            const float S1 = red[cur][0][0] + red[cur][1][0] + red[cur][2][0] + red[cur][3][0];
            const float d0 = red[cur][0][1] + red[cur][1][1] + red[cur][2][1] + red[cur][3][1];
            const float d1 = red[cur][0][2] + red[cur][1][2] + red[cur][2][2] + red[cur][3][2];
            const float d2 = red[cur][0][3] + red[cur][1][3] + red[cur][2][3] + red[cur][3][3];
            const float d3 = red[cur][0][4] + red[cur][1][4] + red[cur][2][4] + red[cur][3][4];
            const float inl = 1.f / fmaxf(sqrtf(S1), 1e-8f);
            const float accv = s0_c.z * (0.5f * d0 * inl / n0_c + 0.5f)
                             + s0_c.w * (0.5f * d1 * inl / n1_c + 0.5f)
                             + s1_c.x * (0.5f * d2 * inl / n2_c + 0.5f)
                             + s1_c.y * (0.5f * d3 * inl / n3_c + 0.5f);
            const float logit = s0_c.x * (accv - s0_c.y);
            stf(out, b * Ss + t, m, 1.f / (1.f + __expf(-logit)));
        }
        // ---- rotate prefetched state ----
        ab_c = ab_n; ab_n = ab_n2;
        pf_c = pf_n; pf_n = pf_n2;
        cpa_c = cpa_n; cpb_c = cpb_n;
        ci1 = ci2;
        s0_c = s0_n; s1_c = s1_n;
        n0_c = n0_n; n1_c = n1_n; n2_c = n2_n; n3_c = n3_n;
    }
    if (tid == 0) stf(out, b * Ss + 199, m, 0.f);
}

extern "C" void kernel_launch(void* const* d_in, const int* in_sizes, int n_in,
                              void* d_out, int out_size, void* d_ws, size_t ws_size,
                              hipStream_t stream) {
    (void)in_sizes; (void)n_in; (void)out_size; (void)ws_size;
    const int* q_seq  = (const int*)d_in[0];
    const int* ha_seq = (const int*)d_in[1];
    const int* c_seq  = (const int*)d_in[2];
    const int* it_seq = (const int*)d_in[3];
    const int* ut_seq = (const int*)d_in[4];
    const int* q2c    = (const int*)d_in[5];
    const int* q2cm   = (const int*)d_in[6];
    const void* Eq   = d_in[7];
    const void* Eqd  = d_in[8];
    const void* Ec   = d_in[9];
    const void* Eit  = d_in[10];
    const void* Eut  = d_in[11];
    const void* Eha  = d_in[12];
    const void* Wf   = d_in[13];
    const void* bfu  = d_in[14];
    const void* Wa   = d_in[15];
    const void* ba   = d_in[16];
    const void* Wg   = d_in[17];
    const void* bg   = d_in[18];
    const void* L0   = d_in[19];

    // workspace layout: mode flag first, small arrays next, 26 MB tail last
    int*   mode   = (int*)d_ws;                 // 16 ints
    float* scal   = (float*)d_ws + 16;          // 199*128*8 = 203776
    int*   cidx   = (int*)(scal + 203776);      // 199*128*4 = 101888
    int*   eidx   = cidx + 101888;              // 101888
    float* Bab    = (float*)(eidx + 101888);    // 384*128 = 49152
    float* Bfg    = Bab + 49152;                // 256*128 = 32768
    float* vA0    = Bfg + 32768;                // 128
    float* vA1    = vA0 + 128;
    float* vF0    = vA1 + 128;
    float* vF1    = vF0 + 128;
    float* cs2    = vF1 + 128;                  // 128
    float* cnorm  = cs2 + 128;                  // 512 (500 used)
    float* absorb = cnorm + 512;                // 199*128*128 = 3260416
    float* pref   = absorb + 3260416;           // 3260416

    hipLaunchKernelGGL(p_detect, dim3(1), dim3(256), 0, stream, Eq, mode);
    hipLaunchKernelGGL(p0_prep, dim3(501), dim3(128), 0, stream, Wf, Ec, mode, cs2, cnorm);
    hipLaunchKernelGGL(p1_weights, dim3(642), dim3(128), 0, stream,
                       Wf, Wa, Wg, bfu, ba, bg, mode, cs2, Bab, Bfg, vA0, vA1, vF0, vF1);
    hipLaunchKernelGGL(p2_rows, dim3(Tt * Bb / 4), dim3(256), 0, stream,
                       q_seq, ha_seq, it_seq, ut_seq, q2c, q2cm,
                       Eq, Eqd, Ec, mode, cnorm, scal, cidx, eidx);
    hipLaunchKernelGGL(p3_gemm, dim3(398, 2), dim3(256), 0, stream,
                       Eq, Eut, Eha, Eit, eidx, c_seq, mode, Bab, Bfg,
                       vA0, vA1, vF0, vF1, absorb, pref);
    hipLaunchKernelGGL(p4_scan, dim3(Bb), dim3(256), 0, stream,
                       Wg, L0, absorb, pref, scal, cidx, cnorm, Ec, mode, d_out);
}

// Round 5
// 339.435 us; speedup vs baseline: 1.4750x; 1.4750x over previous
//
#include <hip/hip_runtime.h>
#include <hip/hip_bf16.h>

typedef unsigned short u16;

#define Bb  128
#define Ss  200
#define Tt  199   // S-1
#define Dd  128
#define Kk  4
#define NQq 10000
#define NCc 500
#define CHK 16    // scan chunk (steps staged per LDS refill)
#define NCH 13    // ceil(199/16)

__device__ inline float bf2f(u16 u) {
    union { unsigned int i; float f; } x;
    x.i = ((unsigned int)u) << 16;
    return x.f;
}

// mode m: 1 = buffers hold fp32, 0 = buffers hold bf16
__device__ inline float ldf(const void* p, int i, int m) {
    if (m) return ((const float*)p)[i];
    return bf2f(((const u16*)p)[i]);
}

__device__ inline void stf(void* p, int i, int m, float v) {
    if (m) ((float*)p)[i] = v;
    else ((__hip_bfloat16*)p)[i] = __float2bfloat16(v);
}

__device__ inline int clampi(int v, int lo, int hi) {
    return v < lo ? lo : (v > hi ? hi : v);
}

__device__ inline float wave_red(float v) {
#pragma unroll
    for (int m = 32; m >= 1; m >>= 1) v += __shfl_xor(v, m);
    return v;
}

// ---------------- Pd: detect input float storage (fp32 vs bf16) ------------
__global__ __launch_bounds__(256) void p_detect(const void* Eq, int* flag) {
    const int tid = threadIdx.x;
    const u16* q = (const u16*)Eq;
    float mx = 0.f;
    for (int i = tid; i < 4096; i += 256) {
        float a = fabsf(bf2f(q[i]));
        if (!(a == a)) a = 3.0e38f;  // NaN -> huge
        mx = fmaxf(mx, a);
    }
#pragma unroll
    for (int s = 32; s >= 1; s >>= 1) mx = fmaxf(mx, __shfl_xor(mx, s));
    __shared__ float sm[4];
    if ((tid & 63) == 0) sm[tid >> 6] = mx;
    __syncthreads();
    if (tid == 0) {
        float m2 = fmaxf(fmaxf(sm[0], sm[1]), fmaxf(sm[2], sm[3]));
        flag[0] = (m2 > 1.0e6f) ? 1 : 0;   // bf16 data: ~0.5; fp32-as-bf16: ~1e38
    }
}

// ---------------- P0: cs2 (colsum of W_fuse bottom half) + concept norms ----
__global__ __launch_bounds__(128) void p0_prep(const void* Wf, const void* Ec,
                                               const int* mode,
                                               float* cs2, float* cnorm) {
    const int m = mode[0];
    const int tid = threadIdx.x;
    if (blockIdx.x == 0) {
        float s = 0.f;
        for (int r = 0; r < 128; ++r) s += ldf(Wf, (128 + r) * 128 + tid, m);
        cs2[tid] = s;
    } else {
        const int c = blockIdx.x - 1;  // 0..499
        float v = ldf(Ec, c * 128 + tid, m);
        float s = wave_red(v * v);
        __shared__ float tmp[2];
        if ((tid & 63) == 0) tmp[tid >> 6] = s;
        __syncthreads();
        if (tid == 0) cnorm[c] = fmaxf(sqrtf(tmp[0] + tmp[1]), 1e-8f);
    }
}

// ---------------- P1: folded weight prep -----------------------------------
// Bab rows: [0:128)=Wf_top@WA1, [128:256)=WA2, [256:384)=WA3
// Bfg rows: [0:128)=Wf_top@WF3, [128:256)=WF2
__global__ __launch_bounds__(128) void p1_weights(
    const void* Wf, const void* Wa, const void* Wg,
    const void* bfu, const void* ba, const void* bg,
    const int* mode, const float* cs2, float* Bab, float* Bfg,
    float* vA0, float* vA1, float* vF0, float* vF1) {
    const int m = mode[0];
    const int bi = blockIdx.x, tid = threadIdx.x;
    if (bi < 128) {
        float acc = 0.f;
        for (int j = 0; j < 128; ++j)
            acc += ldf(Wf, bi * 128 + j, m) * ldf(Wa, j * 128 + tid, m);
        Bab[bi * 128 + tid] = acc;
    } else if (bi < 256) {
        const int i = bi - 128;
        float acc = 0.f;
        for (int j = 0; j < 128; ++j)
            acc += ldf(Wf, i * 128 + j, m) * ldf(Wg, (256 + j) * 128 + tid, m);
        Bfg[i * 128 + tid] = acc;
    } else if (bi < 512) {
        const int r = bi - 256 + 128;  // 128..383
        Bab[r * 128 + tid] = ldf(Wa, r * 128 + tid, m);
    } else if (bi < 640) {
        const int r = bi - 512 + 128;  // 128..255
        Bfg[r * 128 + tid] = ldf(Wg, r * 128 + tid, m);
    } else if (bi == 640) {
        float a0 = 0.f, a1 = 0.f;
        for (int j = 0; j < 128; ++j) {
            float wv = ldf(Wa, j * 128 + tid, m);
            a0 += ldf(bfu, j, m) * wv;
            a1 += cs2[j] * wv;
        }
        vA0[tid] = a0 + ldf(ba, tid, m);
        vA1[tid] = a1;
    } else {
        float a0 = 0.f, a1 = 0.f;
        for (int j = 0; j < 128; ++j) {
            float wv = ldf(Wg, (256 + j) * 128 + tid, m);
            a0 += ldf(bfu, j, m) * wv;
            a1 += cs2[j] * wv;
        }
        vF0[tid] = a0 + ldf(bg, tid, m);
        vF1[tid] = a1;
    }
}

// ---------------- P2: per-(t,b) gathers + qdiff (4 rows per block) ---------
__global__ __launch_bounds__(256) void p2_rows(
    const int* q_seq, const int* ha_seq, const int* it_seq, const int* ut_seq,
    const int* q2c, const int* q2cm,
    const void* Eq, const void* Eqd, const void* Ec,
    const int* mode, const float* cnorm,
    float* scal, int* cidx, int* eidx) {
    const int m = mode[0];
    const int wv = threadIdx.x >> 6, lane = threadIdx.x & 63;
    const int r = blockIdx.x * 4 + wv;  // r = t*128 + b; grid*4 == Tt*Bb exactly
    const int t = r >> 7, b = r & 127;
    const int qt  = q_seq[b * Ss + t];
    const int qt1 = q_seq[b * Ss + t + 1];
    const float qa = ldf(Eq, qt * 128 + lane, m);
    const float qb = ldf(Eq, qt * 128 + 64 + lane, m);
    const float nqc = fmaxf(sqrtf(wave_red(qa * qa + qb * qb)), 1e-8f);
    const int4 cc = ((const int4*)q2c)[qt];
    const int4 mm = ((const int4*)q2cm)[qt];
    const int cks[4] = {clampi(cc.x, 0, NCc - 1), clampi(cc.y, 0, NCc - 1),
                        clampi(cc.z, 0, NCc - 1), clampi(cc.w, 0, NCc - 1)};
    const int ms[4]  = {mm.x, mm.y, mm.z, mm.w};
    float qs = 0.f;
#pragma unroll
    for (int k = 0; k < 4; ++k) {
        const int ck = cks[k];
        float dot = wave_red(qa * ldf(Ec, ck * 128 + lane, m) +
                             qb * ldf(Ec, ck * 128 + 64 + lane, m));
        float cosv = dot / (nqc * cnorm[ck]);
        qs += (float)ms[k] * (0.5f * cosv + 0.5f);
    }
    if (lane == 0) {
        const float qd1 = 10.f / (1.f + __expf(-ldf(Eqd, qt1, m)));
        float4 s0 = make_float4(qd1, qs, (float)ms[0], (float)ms[1]);
        float4 s1 = make_float4((float)ms[2], (float)ms[3], 0.f, 0.f);
        ((float4*)scal)[r * 2]     = s0;
        ((float4*)scal)[r * 2 + 1] = s1;
        ((int4*)cidx)[r] = ((const int4*)q2c)[qt1];
        int4 e;
        e.x = qt;
        e.y = ut_seq[b * Ss + t];
        e.z = ha_seq[b * Ss + t];
        e.w = it_seq[b * Ss + t];
        ((int4*)eidx)[r] = e;
    }
}

// ---------------- P3: GEMM  rows x {K=384 -> absorb | K=256 -> pre_forget} --
__global__ __launch_bounds__(256) void p3_gemm(
    const void* Eq, const void* Eut, const void* Eha, const void* Eit,
    const int* eidx, const int* c_seq, const int* mode,
    const float* Bab, const float* Bfg,
    const float* vA0, const float* vA1, const float* vF0, const float* vF1,
    float* absorb, float* pref) {
    __shared__ float At[64][36];
    __shared__ float Bt[32][128];
    __shared__ int eis[64][4];
    __shared__ float cfs[64];
    const int m = mode[0];
    const int tid = threadIdx.x;
    const int r0 = blockIdx.x * 64;
    const int by = blockIdx.y;
    if (tid < 64) {
        const int r = r0 + tid;
        int4 e = ((const int4*)eidx)[r];
        eis[tid][0] = clampi(e.x, 0, NQq - 1);
        eis[tid][1] = clampi(e.y, 0, 99);
        eis[tid][2] = clampi(e.z, 0, 11);
        eis[tid][3] = clampi(e.w, 0, 99);
        cfs[tid] = (float)c_seq[(r & 127) * Ss + (r >> 7)];
    }
    __syncthreads();
    float acc[4][8];
#pragma unroll
    for (int j = 0; j < 4; ++j)
#pragma unroll
        for (int i = 0; i < 8; ++i) acc[j][i] = 0.f;
    const float* Bm = by ? Bfg : Bab;
    const int ng = by ? 2 : 3;
    const int tx = tid & 15, ty = tid >> 4;
    for (int g = 0; g < ng; ++g) {
        const void* tab;
        int comp;
        if (by == 0) { tab = (g == 0) ? Eq : ((g == 1) ? Eut : Eha); comp = g; }
        else         { tab = (g == 0) ? Eq : Eit; comp = (g == 0) ? 0 : 3; }
        for (int ks = 0; ks < 4; ++ks) {
            {   // A tile: 64 rows x 32 k
                const int row = tid >> 2, seg = tid & 3;
                const int ei = eis[row][comp] * 128 + ks * 32 + seg * 8;
                float* dst = &At[row][seg * 8];
                if (m) {
                    const float4* src = (const float4*)((const float*)tab + ei);
                    float4 v0 = src[0], v1 = src[1];
                    dst[0] = v0.x; dst[1] = v0.y; dst[2] = v0.z; dst[3] = v0.w;
                    dst[4] = v1.x; dst[5] = v1.y; dst[6] = v1.z; dst[7] = v1.w;
                } else {
                    uint4 v = *(const uint4*)((const u16*)tab + ei);
                    dst[0] = bf2f((u16)(v.x & 0xffff)); dst[1] = bf2f((u16)(v.x >> 16));
                    dst[2] = bf2f((u16)(v.y & 0xffff)); dst[3] = bf2f((u16)(v.y >> 16));
                    dst[4] = bf2f((u16)(v.z & 0xffff)); dst[5] = bf2f((u16)(v.z >> 16));
                    dst[6] = bf2f((u16)(v.w & 0xffff)); dst[7] = bf2f((u16)(v.w >> 16));
                }
            }
            {   // B tile: 32 x 128
                const float4* Bm4 = (const float4*)(Bm + (g * 128 + ks * 32) * 128);
                float4* Bt4 = (float4*)&Bt[0][0];
#pragma unroll
                for (int k = 0; k < 4; ++k) Bt4[tid + k * 256] = Bm4[tid + k * 256];
            }
            __syncthreads();
#pragma unroll
            for (int kk = 0; kk < 32; kk += 4) {
                float a_[4][4];
                *(float4*)&a_[0][0] = *(const float4*)&At[ty * 4 + 0][kk];
                *(float4*)&a_[1][0] = *(const float4*)&At[ty * 4 + 1][kk];
                *(float4*)&a_[2][0] = *(const float4*)&At[ty * 4 + 2][kk];
                *(float4*)&a_[3][0] = *(const float4*)&At[ty * 4 + 3][kk];
#pragma unroll
                for (int q = 0; q < 4; ++q) {
                    float4 b0 = *(const float4*)&Bt[kk + q][tx * 8];
                    float4 b1 = *(const float4*)&Bt[kk + q][tx * 8 + 4];
#pragma unroll
                    for (int j = 0; j < 4; ++j) {
                        const float av = a_[j][q];
                        acc[j][0] += av * b0.x; acc[j][1] += av * b0.y;
                        acc[j][2] += av * b0.z; acc[j][3] += av * b0.w;
                        acc[j][4] += av * b1.x; acc[j][5] += av * b1.y;
                        acc[j][6] += av * b1.z; acc[j][7] += av * b1.w;
                    }
                }
            }
            __syncthreads();
        }
    }
    const float* v0 = by ? vF0 : vA0;
    const float* v1 = by ? vF1 : vA1;
    float* outbase = by ? pref : absorb;
#pragma unroll
    for (int j = 0; j < 4; ++j) {
        const int row = ty * 4 + j;
        const int r = r0 + row;
        const float cf = cfs[row];
        float* op = outbase + r * 128 + tx * 8;
#pragma unroll
        for (int i = 0; i < 8; ++i) {
            const int dd = tx * 8 + i;
            op[i] = acc[j][i] + v0[dd] + cf * v1[dd];
        }
    }
}

// ---------------- P4: minimal sequential scan ------------------------------
// Only the irreducible recurrence: fs = lp@WF1, lc = lp*sigmoid(fs+pf)+ab.
// lc history overwrites absorb in place (row t consumed exactly at step t).
// absorb/pref staged in 16-step chunks: global->regs (16 steps ahead) ->LDS.
__global__ __launch_bounds__(256) void p4_scan(
    const void* Wg, const void* L0,
    float* absorb, const float* pref, const int* mode) {
    const int m = mode[0];
    const int b = blockIdx.x;
    const int tid = threadIdx.x;
    const int d = tid >> 1, half = tid & 1;
    __shared__ float lp[2][128];
    __shared__ float st[2][CHK * 128];  // [0]=ab, [1]=pf for current chunk
    float w[64];
#pragma unroll
    for (int i = 0; i < 64; ++i)
        w[i] = ldf(Wg, (half * 64 + i) * 128 + d, m);   // WF1[i_global][d]
    float lc = ldf(L0, b * 128 + d, m);
    if (half == 0) lp[0][d] = lc;

    // chunk staging assignment: thread -> (row srow in chunk, 8-float seg)
    const int srow = tid >> 4, seg = tid & 15;
    float4 rab0, rab1, rpf0, rpf1;
    {   // load chunk 0 into regs
        int tt = srow; if (tt > Tt - 1) tt = Tt - 1;
        const float4* pa = (const float4*)(absorb + ((long)tt * 128 + b) * 128) + seg * 2;
        const float4* pp = (const float4*)(pref   + ((long)tt * 128 + b) * 128) + seg * 2;
        rab0 = pa[0]; rab1 = pa[1]; rpf0 = pp[0]; rpf1 = pp[1];
    }

    for (int c = 0; c < NCH; ++c) {
        // publish staged chunk to LDS
        {
            float4* sa = (float4*)&st[0][srow * 128 + seg * 8];
            sa[0] = rab0; sa[1] = rab1;
            float4* sp = (float4*)&st[1][srow * 128 + seg * 8];
            sp[0] = rpf0; sp[1] = rpf1;
        }
        __syncthreads();
        // issue next chunk's loads (consumed 16 steps from now)
        if (c + 1 < NCH) {
            int tt = (c + 1) * CHK + srow; if (tt > Tt - 1) tt = Tt - 1;
            const float4* pa = (const float4*)(absorb + ((long)tt * 128 + b) * 128) + seg * 2;
            const float4* pp = (const float4*)(pref   + ((long)tt * 128 + b) * 128) + seg * 2;
            rab0 = pa[0]; rab1 = pa[1]; rpf0 = pp[0]; rpf1 = pp[1];
        }
        const int smax = (Tt - c * CHK < CHK) ? (Tt - c * CHK) : CHK;
        for (int s = 0; s < smax; ++s) {
            const int t = c * CHK + s;
            const int cur = t & 1;
            // matvec lp @ WF1 (this thread's 64-i half) — LDS broadcast reads
            const float* lpc = &lp[cur][half * 64];
            float fs = 0.f;
#pragma unroll
            for (int i = 0; i < 64; i += 4) {
                float4 v = *(const float4*)(lpc + i);
                fs += w[i] * v.x + w[i + 1] * v.y + w[i + 2] * v.z + w[i + 3] * v.w;
            }
            fs += __shfl_xor(fs, 1);  // combine the (d) pair's halves
            if (half == 0) {
                const float ab = st[0][s * 128 + d];
                const float pf = st[1][s * 128 + d];
                const float forget = 1.f / (1.f + __expf(-(fs + pf)));
                lc = lc * forget + ab;
                lp[cur ^ 1][d] = lc;
                absorb[((long)t * 128 + b) * 128 + d] = lc;  // lc history, in place
            }
            __syncthreads();
        }
    }
}

// ---------------- P5: parallel cosine/logit epilogue (one wave per row) ----
__global__ __launch_bounds__(256) void p5_out(
    const float* lc_seq, const float* scal, const int* cidx, const float* cnorm,
    const void* Ec, const int* mode, void* out) {
    const int m = mode[0];
    const int wv = threadIdx.x >> 6, lane = threadIdx.x & 63;
    const int r = blockIdx.x * 4 + wv;  // 6368*4 == 25472 == Tt*Bb
    const int t = r >> 7, b = r & 127;
    const float la = lc_seq[(long)r * 128 + lane];
    const float lb = lc_seq[(long)r * 128 + 64 + lane];
    int4 ci = ((const int4*)cidx)[r];
    const int c0 = clampi(ci.x, 0, NCc - 1), c1 = clampi(ci.y, 0, NCc - 1);
    const int c2 = clampi(ci.z, 0, NCc - 1), c3 = clampi(ci.w, 0, NCc - 1);
    float nl = la * la + lb * lb;
    float d0 = la * ldf(Ec, c0 * 128 + lane, m) + lb * ldf(Ec, c0 * 128 + 64 + lane, m);
    float d1 = la * ldf(Ec, c1 * 128 + lane, m) + lb * ldf(Ec, c1 * 128 + 64 + lane, m);
    float d2 = la * ldf(Ec, c2 * 128 + lane, m) + lb * ldf(Ec, c2 * 128 + 64 + lane, m);
    float d3 = la * ldf(Ec, c3 * 128 + lane, m) + lb * ldf(Ec, c3 * 128 + 64 + lane, m);
#pragma unroll
    for (int s = 32; s >= 1; s >>= 1) {
        nl += __shfl_xor(nl, s);
        d0 += __shfl_xor(d0, s); d1 += __shfl_xor(d1, s);
        d2 += __shfl_xor(d2, s); d3 += __shfl_xor(d3, s);
    }
    if (lane == 0) {
        const float4 s0 = ((const float4*)scal)[r * 2];
        const float4 s1 = ((const float4*)scal)[r * 2 + 1];
        const float n0 = cnorm[c0], n1 = cnorm[c1], n2 = cnorm[c2], n3 = cnorm[c3];
        const float inl = 1.f / fmaxf(sqrtf(nl), 1e-8f);
        const float accv = s0.z * (0.5f * d0 * inl / n0 + 0.5f)
                         + s0.w * (0.5f * d1 * inl / n1 + 0.5f)
                         + s1.x * (0.5f * d2 * inl / n2 + 0.5f)
                         + s1.y * (0.5f * d3 * inl / n3 + 0.5f);
        const float logit = s0.x * (accv - s0.y);
        stf(out, b * Ss + t, m, 1.f / (1.f + __expf(-logit)));
        if (t == 0) stf(out, b * Ss + 199, m, 0.f);
    }
}

extern "C" void kernel_launch(void* const* d_in, const int* in_sizes, int n_in,
                              void* d_out, int out_size, void* d_ws, size_t ws_size,
                              hipStream_t stream) {
    (void)in_sizes; (void)n_in; (void)out_size; (void)ws_size;
    const int* q_seq  = (const int*)d_in[0];
    const int* ha_seq = (const int*)d_in[1];
    const int* c_seq  = (const int*)d_in[2];
    const int* it_seq = (const int*)d_in[3];
    const int* ut_seq = (const int*)d_in[4];
    const int* q2c    = (const int*)d_in[5];
    const int* q2cm   = (const int*)d_in[6];
    const void* Eq   = d_in[7];
    const void* Eqd  = d_in[8];
    const void* Ec   = d_in[9];
    const void* Eit  = d_in[10];
    const void* Eut  = d_in[11];
    const void* Eha  = d_in[12];
    const void* Wf   = d_in[13];
    const void* bfu  = d_in[14];
    const void* Wa   = d_in[15];
    const void* ba   = d_in[16];
    const void* Wg   = d_in[17];
    const void* bg   = d_in[18];
    const void* L0   = d_in[19];

    // workspace layout: mode flag first, small arrays next, 26 MB tail last
    int*   mode   = (int*)d_ws;                 // 16 ints
    float* scal   = (float*)d_ws + 16;          // 199*128*8 = 203776
    int*   cidx   = (int*)(scal + 203776);      // 199*128*4 = 101888
    int*   eidx   = cidx + 101888;              // 101888
    float* Bab    = (float*)(eidx + 101888);    // 384*128 = 49152
    float* Bfg    = Bab + 49152;                // 256*128 = 32768
    float* vA0    = Bfg + 32768;                // 128
    float* vA1    = vA0 + 128;
    float* vF0    = vA1 + 128;
    float* vF1    = vF0 + 128;
    float* cs2    = vF1 + 128;                  // 128
    float* cnorm  = cs2 + 128;                  // 512 (500 used)
    float* absorb = cnorm + 512;                // 199*128*128 = 3260416 (becomes lc history)
    float* pref   = absorb + 3260416;           // 3260416

    hipLaunchKernelGGL(p_detect, dim3(1), dim3(256), 0, stream, Eq, mode);
    hipLaunchKernelGGL(p0_prep, dim3(501), dim3(128), 0, stream, Wf, Ec, mode, cs2, cnorm);
    hipLaunchKernelGGL(p1_weights, dim3(642), dim3(128), 0, stream,
                       Wf, Wa, Wg, bfu, ba, bg, mode, cs2, Bab, Bfg, vA0, vA1, vF0, vF1);
    hipLaunchKernelGGL(p2_rows, dim3(Tt * Bb / 4), dim3(256), 0, stream,
                       q_seq, ha_seq, it_seq, ut_seq, q2c, q2cm,
                       Eq, Eqd, Ec, mode, cnorm, scal, cidx, eidx);
    hipLaunchKernelGGL(p3_gemm, dim3(398, 2), dim3(256), 0, stream,
                       Eq, Eut, Eha, Eit, eidx, c_seq, mode, Bab, Bfg,
                       vA0, vA1, vF0, vF1, absorb, pref);
    hipLaunchKernelGGL(p4_scan, dim3(Bb), dim3(256), 0, stream,
                       Wg, L0, absorb, pref, mode);
    hipLaunchKernelGGL(p5_out, dim3(Tt * Bb / 4), dim3(256), 0, stream,
                       absorb, scal, cidx, cnorm, Ec, mode, d_out);
}

// Round 6
// 271.172 us; speedup vs baseline: 1.8463x; 1.2517x over previous
//
#include <hip/hip_runtime.h>
#include <hip/hip_bf16.h>

typedef unsigned short u16;

#define Bb  128
#define Ss  200
#define Tt  199   // S-1
#define Dd  128
#define Kk  4
#define NQq 10000
#define NCc 500
#define CHK 16    // scan chunk (steps staged per refill)
#define NCH 13    // ceil(199/16)

__device__ inline float bf2f(u16 u) {
    union { unsigned int i; float f; } x;
    x.i = ((unsigned int)u) << 16;
    return x.f;
}

// mode m: 1 = buffers hold fp32, 0 = buffers hold bf16
__device__ inline float ldf(const void* p, int i, int m) {
    if (m) return ((const float*)p)[i];
    return bf2f(((const u16*)p)[i]);
}

__device__ inline void stf(void* p, int i, int m, float v) {
    if (m) ((float*)p)[i] = v;
    else ((__hip_bfloat16*)p)[i] = __float2bfloat16(v);
}

__device__ inline int clampi(int v, int lo, int hi) {
    return v < lo ? lo : (v > hi ? hi : v);
}

__device__ inline float wave_red(float v) {
#pragma unroll
    for (int m = 32; m >= 1; m >>= 1) v += __shfl_xor(v, m);
    return v;
}

__device__ inline float4 f4add(float4 a, float4 b) {
    return make_float4(a.x + b.x, a.y + b.y, a.z + b.z, a.w + b.w);
}
__device__ inline float4 f4fma(float s, float4 a, float4 b) {
    return make_float4(fmaf(s, a.x, b.x), fmaf(s, a.y, b.y),
                       fmaf(s, a.z, b.z), fmaf(s, a.w, b.w));
}

// ---------------- Pd: detect input float storage (fp32 vs bf16) ------------
__global__ __launch_bounds__(256) void p_detect(const void* Eq, int* flag) {
    const int tid = threadIdx.x;
    const u16* q = (const u16*)Eq;
    float mx = 0.f;
    for (int i = tid; i < 4096; i += 256) {
        float a = fabsf(bf2f(q[i]));
        if (!(a == a)) a = 3.0e38f;  // NaN -> huge
        mx = fmaxf(mx, a);
    }
#pragma unroll
    for (int s = 32; s >= 1; s >>= 1) mx = fmaxf(mx, __shfl_xor(mx, s));
    __shared__ float sm[4];
    if ((tid & 63) == 0) sm[tid >> 6] = mx;
    __syncthreads();
    if (tid == 0) {
        float m2 = fmaxf(fmaxf(sm[0], sm[1]), fmaxf(sm[2], sm[3]));
        flag[0] = (m2 > 1.0e6f) ? 1 : 0;
    }
}

// ---------------- P0: cs2 (colsum W_fuse bottom) + concept norms -----------
__global__ __launch_bounds__(128) void p0_prep(const void* Wf, const void* Ec,
                                               const int* mode,
                                               float* cs2, float* cnorm) {
    const int m = mode[0];
    const int tid = threadIdx.x;
    if (blockIdx.x == 0) {
        float s = 0.f;
        for (int r = 0; r < 128; ++r) s += ldf(Wf, (128 + r) * 128 + tid, m);
        cs2[tid] = s;
    } else {
        const int c = blockIdx.x - 1;  // 0..499
        float v = ldf(Ec, c * 128 + tid, m);
        float s = wave_red(v * v);
        __shared__ float tmp[2];
        if ((tid & 63) == 0) tmp[tid >> 6] = s;
        __syncthreads();
        if (tid == 0) cnorm[c] = fmaxf(sqrtf(tmp[0] + tmp[1]), 1e-8f);
    }
}

// ---------------- P1: folded weights + bias vecs + small-table products ----
// BabT = Wf_top@WA1 (128x128); BfgT = Wf_top@WF3 (128x128)
// PA_ut = Eut@WA2 (100x128); PA_ha = Eha@WA3 (12x128); PF_it = Eit@WF2 (100x128)
__global__ __launch_bounds__(128) void p1_weights(
    const void* Wf, const void* Wa, const void* Wg,
    const void* bfu, const void* ba, const void* bg,
    const void* Eut, const void* Eha, const void* Eit,
    const int* mode, const float* cs2,
    float* BabT, float* BfgT,
    float* vA0, float* vA1, float* vF0, float* vF1,
    float* PA_ut, float* PA_ha, float* PF_it) {
    const int m = mode[0];
    const int bi = blockIdx.x, tid = threadIdx.x;
    if (bi < 128) {
        float acc = 0.f;
        for (int j = 0; j < 128; ++j)
            acc += ldf(Wf, bi * 128 + j, m) * ldf(Wa, j * 128 + tid, m);
        BabT[bi * 128 + tid] = acc;
    } else if (bi < 256) {
        const int i = bi - 128;
        float acc = 0.f;
        for (int j = 0; j < 128; ++j)
            acc += ldf(Wf, i * 128 + j, m) * ldf(Wg, (256 + j) * 128 + tid, m);
        BfgT[i * 128 + tid] = acc;
    } else if (bi == 256) {
        float a0 = 0.f, a1 = 0.f;
        for (int j = 0; j < 128; ++j) {
            float wv = ldf(Wa, j * 128 + tid, m);
            a0 += ldf(bfu, j, m) * wv;
            a1 += cs2[j] * wv;
        }
        vA0[tid] = a0 + ldf(ba, tid, m);
        vA1[tid] = a1;
    } else if (bi == 257) {
        float a0 = 0.f, a1 = 0.f;
        for (int j = 0; j < 128; ++j) {
            float wv = ldf(Wg, (256 + j) * 128 + tid, m);
            a0 += ldf(bfu, j, m) * wv;
            a1 += cs2[j] * wv;
        }
        vF0[tid] = a0 + ldf(bg, tid, m);
        vF1[tid] = a1;
    } else if (bi < 358) {
        const int r = bi - 258;  // 0..99: PA_ut
        float acc = 0.f;
        for (int j = 0; j < 128; ++j)
            acc += ldf(Eut, r * 128 + j, m) * ldf(Wa, (128 + j) * 128 + tid, m);
        PA_ut[r * 128 + tid] = acc;
    } else if (bi < 370) {
        const int r = bi - 358;  // 0..11: PA_ha
        float acc = 0.f;
        for (int j = 0; j < 128; ++j)
            acc += ldf(Eha, r * 128 + j, m) * ldf(Wa, (256 + j) * 128 + tid, m);
        PA_ha[r * 128 + tid] = acc;
    } else {
        const int r = bi - 370;  // 0..99: PF_it
        float acc = 0.f;
        for (int j = 0; j < 128; ++j)
            acc += ldf(Eit, r * 128 + j, m) * ldf(Wg, (128 + j) * 128 + tid, m);
        PF_it[r * 128 + tid] = acc;
    }
}

// ---------------- P3: per-question GEMM  PA_q = Eq@BabT, PF_q = Eq@BfgT ----
__global__ __launch_bounds__(256) void p3_gemm(
    const void* Eq, const int* mode,
    const float* BabT, const float* BfgT,
    float* PA_q, float* PF_q) {
    __shared__ float At[64][36];
    __shared__ float Bt0[32][128];
    __shared__ float Bt1[32][128];
    const int m = mode[0];
    const int tid = threadIdx.x;
    const int r0 = blockIdx.x * 64;
    float acc0[4][8], acc1[4][8];
#pragma unroll
    for (int j = 0; j < 4; ++j)
#pragma unroll
        for (int i = 0; i < 8; ++i) { acc0[j][i] = 0.f; acc1[j][i] = 0.f; }
    const int tx = tid & 15, ty = tid >> 4;
    for (int ks = 0; ks < 4; ++ks) {
        {   // A tile: 64 rows x 32 k from Eq (rows direct)
            const int row = tid >> 2, seg = tid & 3;
            const int q = clampi(r0 + row, 0, NQq - 1);
            const int ei = q * 128 + ks * 32 + seg * 8;
            float* dst = &At[row][seg * 8];
            if (m) {
                const float4* src = (const float4*)((const float*)Eq + ei);
                float4 v0 = src[0], v1 = src[1];
                dst[0] = v0.x; dst[1] = v0.y; dst[2] = v0.z; dst[3] = v0.w;
                dst[4] = v1.x; dst[5] = v1.y; dst[6] = v1.z; dst[7] = v1.w;
            } else {
                uint4 v = *(const uint4*)((const u16*)Eq + ei);
                dst[0] = bf2f((u16)(v.x & 0xffff)); dst[1] = bf2f((u16)(v.x >> 16));
                dst[2] = bf2f((u16)(v.y & 0xffff)); dst[3] = bf2f((u16)(v.y >> 16));
                dst[4] = bf2f((u16)(v.z & 0xffff)); dst[5] = bf2f((u16)(v.z >> 16));
                dst[6] = bf2f((u16)(v.w & 0xffff)); dst[7] = bf2f((u16)(v.w >> 16));
            }
        }
        {   // B tiles (fp32 ws)
            const float4* s0 = (const float4*)(BabT + ks * 32 * 128);
            const float4* s1 = (const float4*)(BfgT + ks * 32 * 128);
            float4* d0 = (float4*)&Bt0[0][0];
            float4* d1 = (float4*)&Bt1[0][0];
#pragma unroll
            for (int k = 0; k < 4; ++k) {
                d0[tid + k * 256] = s0[tid + k * 256];
                d1[tid + k * 256] = s1[tid + k * 256];
            }
        }
        __syncthreads();
#pragma unroll
        for (int kk = 0; kk < 32; kk += 4) {
            float a_[4][4];
            *(float4*)&a_[0][0] = *(const float4*)&At[ty * 4 + 0][kk];
            *(float4*)&a_[1][0] = *(const float4*)&At[ty * 4 + 1][kk];
            *(float4*)&a_[2][0] = *(const float4*)&At[ty * 4 + 2][kk];
            *(float4*)&a_[3][0] = *(const float4*)&At[ty * 4 + 3][kk];
#pragma unroll
            for (int q = 0; q < 4; ++q) {
                float4 b0 = *(const float4*)&Bt0[kk + q][tx * 8];
                float4 b1 = *(const float4*)&Bt0[kk + q][tx * 8 + 4];
                float4 c0 = *(const float4*)&Bt1[kk + q][tx * 8];
                float4 c1 = *(const float4*)&Bt1[kk + q][tx * 8 + 4];
#pragma unroll
                for (int j = 0; j < 4; ++j) {
                    const float av = a_[j][q];
                    acc0[j][0] += av * b0.x; acc0[j][1] += av * b0.y;
                    acc0[j][2] += av * b0.z; acc0[j][3] += av * b0.w;
                    acc0[j][4] += av * b1.x; acc0[j][5] += av * b1.y;
                    acc0[j][6] += av * b1.z; acc0[j][7] += av * b1.w;
                    acc1[j][0] += av * c0.x; acc1[j][1] += av * c0.y;
                    acc1[j][2] += av * c0.z; acc1[j][3] += av * c0.w;
                    acc1[j][4] += av * c1.x; acc1[j][5] += av * c1.y;
                    acc1[j][6] += av * c1.z; acc1[j][7] += av * c1.w;
                }
            }
        }
        __syncthreads();
    }
#pragma unroll
    for (int j = 0; j < 4; ++j) {
        const int q = r0 + ty * 4 + j;
        if (q < NQq) {
            float* oa = PA_q + q * 128 + tx * 8;
            float* of = PF_q + q * 128 + tx * 8;
#pragma unroll
            for (int i = 0; i < 8; ++i) { oa[i] = acc0[j][i]; of[i] = acc1[j][i]; }
        }
    }
}

// ---------------- P2q: per-question qdm (masked qdiff sum) + qd10 ----------
__global__ __launch_bounds__(256) void p2q(
    const int* q2c, const int* q2cm,
    const void* Eq, const void* Eqd, const void* Ec,
    const int* mode, const float* cnorm,
    float* qdm, float* qd10) {
    const int m = mode[0];
    const int wv = threadIdx.x >> 6, lane = threadIdx.x & 63;
    const int q = blockIdx.x * 4 + wv;  // 2500*4 == 10000
    const float qa = ldf(Eq, q * 128 + lane, m);
    const float qb = ldf(Eq, q * 128 + 64 + lane, m);
    const float nqc = fmaxf(sqrtf(wave_red(qa * qa + qb * qb)), 1e-8f);
    const int4 cc = ((const int4*)q2c)[q];
    const int4 mm = ((const int4*)q2cm)[q];
    const int cks[4] = {clampi(cc.x, 0, NCc - 1), clampi(cc.y, 0, NCc - 1),
                        clampi(cc.z, 0, NCc - 1), clampi(cc.w, 0, NCc - 1)};
    const int ms[4]  = {mm.x, mm.y, mm.z, mm.w};
    float qs = 0.f;
#pragma unroll
    for (int k = 0; k < 4; ++k) {
        const int ck = cks[k];
        float dot = wave_red(qa * ldf(Ec, ck * 128 + lane, m) +
                             qb * ldf(Ec, ck * 128 + 64 + lane, m));
        qs += (float)ms[k] * (0.5f * dot / (nqc * cnorm[ck]) + 0.5f);
    }
    if (lane == 0) {
        qdm[q] = qs;
        qd10[q] = 10.f / (1.f + __expf(-ldf(Eqd, q, m)));
    }
}

// ---------------- P4: minimal scan, wave-partial matvec --------------------
// wave w owns i-range [32w,32w+32); lane l owns d=2l,2l+1 (W in regs).
// lp reads are wave-uniform LDS broadcasts; partials exchanged via 2KB LDS.
// ab/pf assembled from per-table gathers, staged 16 steps ahead.
__global__ __launch_bounds__(256) void p4_scan(
    const int* q_seq, const int* ut_seq, const int* ha_seq, const int* it_seq,
    const int* c_seq,
    const void* Wg, const void* L0,
    const float* PA_q, const float* PA_ut, const float* PA_ha,
    const float* PF_q, const float* PF_it,
    const float* vA0, const float* vA1, const float* vF0, const float* vF1,
    const int* mode, float* lc_seq) {
    const int m = mode[0];
    const int b = blockIdx.x;
    const int tid = threadIdx.x;
    const int wv = tid >> 6, l = tid & 63;
    const int d0 = 2 * l, ib = wv * 32;

    __shared__ float lp_sh[128];
    __shared__ float part[512];
    __shared__ float st_ab[CHK * 128];
    __shared__ float st_pf[CHK * 128];

    float wA[32], wB[32];
#pragma unroll
    for (int k = 0; k < 32; ++k) {
        wA[k] = ldf(Wg, (ib + k) * 128 + d0, m);
        wB[k] = ldf(Wg, (ib + k) * 128 + d0 + 1, m);
    }
    float lc = 0.f;
    if (tid < 128) {
        lc = ldf(L0, b * 128 + tid, m);
        lp_sh[tid] = lc;
    }

    // staging role: thread -> (row srow in chunk, 8-float segment seg)
    const int srow = tid >> 4, seg = tid & 15;
    const int off8 = seg * 8;
    const float4 A0a = *(const float4*)(vA0 + off8), A0b = *(const float4*)(vA0 + off8 + 4);
    const float4 A1a = *(const float4*)(vA1 + off8), A1b = *(const float4*)(vA1 + off8 + 4);
    const float4 F0a = *(const float4*)(vF0 + off8), F0b = *(const float4*)(vF0 + off8 + 4);
    const float4 F1a = *(const float4*)(vF1 + off8), F1b = *(const float4*)(vF1 + off8 + 4);

    float4 qa0, qa1, ua0, ua1, ga0, ga1, qf0, qf1, if0, if1;
    float cf;
#define LOAD_CHUNK(C)                                                          \
    {                                                                          \
        int tt = (C) * CHK + srow; if (tt > Tt - 1) tt = Tt - 1;               \
        const int base = b * Ss + tt;                                          \
        const int qt = clampi(q_seq[base], 0, NQq - 1);                        \
        const int ut = clampi(ut_seq[base], 0, 99);                            \
        const int ha = clampi(ha_seq[base], 0, 11);                            \
        const int it = clampi(it_seq[base], 0, 99);                            \
        cf = (float)c_seq[base];                                               \
        const float* pq = PA_q + qt * 128 + off8;                              \
        qa0 = *(const float4*)pq; qa1 = *(const float4*)(pq + 4);              \
        const float* pu = PA_ut + ut * 128 + off8;                             \
        ua0 = *(const float4*)pu; ua1 = *(const float4*)(pu + 4);              \
        const float* ph = PA_ha + ha * 128 + off8;                             \
        ga0 = *(const float4*)ph; ga1 = *(const float4*)(ph + 4);              \
        const float* pf = PF_q + qt * 128 + off8;                              \
        qf0 = *(const float4*)pf; qf1 = *(const float4*)(pf + 4);              \
        const float* pi = PF_it + it * 128 + off8;                             \
        if0 = *(const float4*)pi; if1 = *(const float4*)(pi + 4);              \
    }

    LOAD_CHUNK(0)
    float lcbuf[CHK];

    for (int c = 0; c < NCH; ++c) {
        // publish staged chunk c
        {
            float4 ab0 = f4fma(cf, A1a, f4add(f4add(qa0, ua0), f4add(ga0, A0a)));
            float4 ab1 = f4fma(cf, A1b, f4add(f4add(qa1, ua1), f4add(ga1, A0b)));
            float4 pf0 = f4fma(cf, F1a, f4add(qf0, f4add(if0, F0a)));
            float4 pf1 = f4fma(cf, F1b, f4add(qf1, f4add(if1, F0b)));
            float4* sa = (float4*)(st_ab + srow * 128 + off8);
            sa[0] = ab0; sa[1] = ab1;
            float4* sp = (float4*)(st_pf + srow * 128 + off8);
            sp[0] = pf0; sp[1] = pf1;
        }
        if (c + 1 < NCH) LOAD_CHUNK(c + 1)
        __syncthreads();   // st (and, at c=0, lp init) visible

#pragma unroll
        for (int s = 0; s < CHK; ++s) {
            // phase A: all waves — partial matvec via uniform lp broadcasts
            const float4* lp4 = (const float4*)(lp_sh + ib);
            float pa = 0.f, pb = 0.f;
#pragma unroll
            for (int k = 0; k < 8; ++k) {
                float4 v = lp4[k];
                pa += v.x * wA[4 * k] + v.y * wA[4 * k + 1]
                    + v.z * wA[4 * k + 2] + v.w * wA[4 * k + 3];
                pb += v.x * wB[4 * k] + v.y * wB[4 * k + 1]
                    + v.z * wB[4 * k + 2] + v.w * wB[4 * k + 3];
            }
            *(float2*)(part + (wv << 7) + d0) = make_float2(pa, pb);
            __syncthreads();
            // phase B: threads 0..127 reduce + recurrence
            if (tid < 128) {
                const float fs = part[tid] + part[128 + tid]
                               + part[256 + tid] + part[384 + tid];
                const float ab = st_ab[(s << 7) + tid];
                const float pf = st_pf[(s << 7) + tid];
                const float fg = 1.f / (1.f + __expf(-(fs + pf)));
                lc = lc * fg + ab;
                lp_sh[tid] = lc;
                lcbuf[s] = lc;
            }
            __syncthreads();
        }
        // flush lc history for chunk c (store drain amortized per chunk)
        if (tid < 128) {
#pragma unroll
            for (int s = 0; s < CHK; ++s) {
                const int t = c * CHK + s;
                if (t < Tt)
                    lc_seq[((long)t * 128 + b) * 128 + tid] = lcbuf[s];
            }
        }
    }
#undef LOAD_CHUNK
}

// ---------------- P5: parallel cosine/logit epilogue (one wave per row) ----
__global__ __launch_bounds__(256) void p5_out(
    const int* q_seq, const int* q2c, const int* q2cm,
    const float* lc_seq, const float* qdm, const float* qd10,
    const float* cnorm, const void* Ec, const int* mode, void* out) {
    const int m = mode[0];
    const int wv = threadIdx.x >> 6, lane = threadIdx.x & 63;
    const int r = blockIdx.x * 4 + wv;  // 6368*4 == 25472 == Tt*Bb
    const int t = r >> 7, b = r & 127;
    const int qt  = clampi(q_seq[b * Ss + t], 0, NQq - 1);
    const int qt1 = clampi(q_seq[b * Ss + t + 1], 0, NQq - 1);
    const int4 mm = ((const int4*)q2cm)[qt];
    int4 ci = ((const int4*)q2c)[qt1];
    const int c0 = clampi(ci.x, 0, NCc - 1), c1 = clampi(ci.y, 0, NCc - 1);
    const int c2 = clampi(ci.z, 0, NCc - 1), c3 = clampi(ci.w, 0, NCc - 1);
    const float la = lc_seq[(long)r * 128 + lane];
    const float lb = lc_seq[(long)r * 128 + 64 + lane];
    float nl = la * la + lb * lb;
    float d0 = la * ldf(Ec, c0 * 128 + lane, m) + lb * ldf(Ec, c0 * 128 + 64 + lane, m);
    float d1 = la * ldf(Ec, c1 * 128 + lane, m) + lb * ldf(Ec, c1 * 128 + 64 + lane, m);
    float d2 = la * ldf(Ec, c2 * 128 + lane, m) + lb * ldf(Ec, c2 * 128 + 64 + lane, m);
    float d3 = la * ldf(Ec, c3 * 128 + lane, m) + lb * ldf(Ec, c3 * 128 + 64 + lane, m);
#pragma unroll
    for (int s = 32; s >= 1; s >>= 1) {
        nl += __shfl_xor(nl, s);
        d0 += __shfl_xor(d0, s); d1 += __shfl_xor(d1, s);
        d2 += __shfl_xor(d2, s); d3 += __shfl_xor(d3, s);
    }
    if (lane == 0) {
        const float inl = 1.f / fmaxf(sqrtf(nl), 1e-8f);
        const float accv = (float)mm.x * (0.5f * d0 * inl / cnorm[c0] + 0.5f)
                         + (float)mm.y * (0.5f * d1 * inl / cnorm[c1] + 0.5f)
                         + (float)mm.z * (0.5f * d2 * inl / cnorm[c2] + 0.5f)
                         + (float)mm.w * (0.5f * d3 * inl / cnorm[c3] + 0.5f);
        const float logit = qd10[qt1] * (accv - qdm[qt]);
        stf(out, b * Ss + t, m, 1.f / (1.f + __expf(-logit)));
        if (t == 0) stf(out, b * Ss + 199, m, 0.f);
    }
}

extern "C" void kernel_launch(void* const* d_in, const int* in_sizes, int n_in,
                              void* d_out, int out_size, void* d_ws, size_t ws_size,
                              hipStream_t stream) {
    (void)in_sizes; (void)n_in; (void)out_size; (void)ws_size;
    const int* q_seq  = (const int*)d_in[0];
    const int* ha_seq = (const int*)d_in[1];
    const int* c_seq  = (const int*)d_in[2];
    const int* it_seq = (const int*)d_in[3];
    const int* ut_seq = (const int*)d_in[4];
    const int* q2c    = (const int*)d_in[5];
    const int* q2cm   = (const int*)d_in[6];
    const void* Eq   = d_in[7];
    const void* Eqd  = d_in[8];
    const void* Ec   = d_in[9];
    const void* Eit  = d_in[10];
    const void* Eut  = d_in[11];
    const void* Eha  = d_in[12];
    const void* Wf   = d_in[13];
    const void* bfu  = d_in[14];
    const void* Wa   = d_in[15];
    const void* ba   = d_in[16];
    const void* Wg   = d_in[17];
    const void* bg   = d_in[18];
    const void* L0   = d_in[19];

    // workspace layout (floats) — ~23.6 MB
    int*   mode  = (int*)d_ws;                  // 16 ints
    float* cs2   = (float*)d_ws + 16;           // 128
    float* cnorm = cs2 + 128;                   // 512 (500 used)
    float* vA0   = cnorm + 512;                 // 128 x4
    float* vA1   = vA0 + 128;
    float* vF0   = vA1 + 128;
    float* vF1   = vF0 + 128;
    float* BabT  = vF1 + 128;                   // 16384
    float* BfgT  = BabT + 16384;                // 16384
    float* PA_ut = BfgT + 16384;                // 12800
    float* PA_ha = PA_ut + 12800;               // 1536
    float* PF_it = PA_ha + 1536;                // 12800
    float* qdm   = PF_it + 12800;               // 10016
    float* qd10  = qdm + 10016;                 // 10016
    float* PA_q  = qd10 + 10016;                // 1,280,000
    float* PF_q  = PA_q + 1280000;              // 1,280,000
    float* lc_seq= PF_q + 1280000;              // 3,260,416

    hipLaunchKernelGGL(p_detect, dim3(1), dim3(256), 0, stream, Eq, mode);
    hipLaunchKernelGGL(p0_prep, dim3(501), dim3(128), 0, stream, Wf, Ec, mode, cs2, cnorm);
    hipLaunchKernelGGL(p1_weights, dim3(470), dim3(128), 0, stream,
                       Wf, Wa, Wg, bfu, ba, bg, Eut, Eha, Eit, mode, cs2,
                       BabT, BfgT, vA0, vA1, vF0, vF1, PA_ut, PA_ha, PF_it);
    hipLaunchKernelGGL(p3_gemm, dim3(157), dim3(256), 0, stream,
                       Eq, mode, BabT, BfgT, PA_q, PF_q);
    hipLaunchKernelGGL(p2q, dim3(2500), dim3(256), 0, stream,
                       q2c, q2cm, Eq, Eqd, Ec, mode, cnorm, qdm, qd10);
    hipLaunchKernelGGL(p4_scan, dim3(Bb), dim3(256), 0, stream,
                       q_seq, ut_seq, ha_seq, it_seq, c_seq, Wg, L0,
                       PA_q, PA_ut, PA_ha, PF_q, PF_it,
                       vA0, vA1, vF0, vF1, mode, lc_seq);
    hipLaunchKernelGGL(p5_out, dim3(Tt * Bb / 4), dim3(256), 0, stream,
                       q_seq, q2c, q2cm, lc_seq, qdm, qd10, cnorm, Ec, mode, d_out);
}

// Round 7
// 258.645 us; speedup vs baseline: 1.9357x; 1.0484x over previous
//
#include <hip/hip_runtime.h>
#include <hip/hip_bf16.h>

typedef unsigned short u16;

#define Bb  128
#define Ss  200
#define Tt  199   // S-1
#define Dd  128
#define Kk  4
#define NQq 10000
#define NCc 500
#define CHK 16    // scan chunk (steps staged per refill)
#define NCH 13    // ceil(199/16)

__device__ inline float bf2f(u16 u) {
    union { unsigned int i; float f; } x;
    x.i = ((unsigned int)u) << 16;
    return x.f;
}

// mode m: 1 = buffers hold fp32, 0 = buffers hold bf16
__device__ inline float ldf(const void* p, int i, int m) {
    if (m) return ((const float*)p)[i];
    return bf2f(((const u16*)p)[i]);
}

__device__ inline void stf(void* p, int i, int m, float v) {
    if (m) ((float*)p)[i] = v;
    else ((__hip_bfloat16*)p)[i] = __float2bfloat16(v);
}

__device__ inline int clampi(int v, int lo, int hi) {
    return v < lo ? lo : (v > hi ? hi : v);
}

__device__ inline float wave_red(float v) {
#pragma unroll
    for (int m = 32; m >= 1; m >>= 1) v += __shfl_xor(v, m);
    return v;
}

__device__ inline float4 f4add(float4 a, float4 b) {
    return make_float4(a.x + b.x, a.y + b.y, a.z + b.z, a.w + b.w);
}
__device__ inline float4 f4fma(float s, float4 a, float4 b) {
    return make_float4(fmaf(s, a.x, b.x), fmaf(s, a.y, b.y),
                       fmaf(s, a.z, b.z), fmaf(s, a.w, b.w));
}

// per-block inline dtype detection: scan first 256 u16 of Eq as bf16.
// fp32 data reinterpreted as bf16 shows huge/NaN values w.p. 1-1e-31.
__device__ inline int detect_mode(const void* Eq) {
    const u16* q = (const u16*)Eq;
    const int l = threadIdx.x & 63;
    float mx = 0.f;
#pragma unroll
    for (int k = 0; k < 4; ++k) {
        float a = fabsf(bf2f(q[l * 4 + k]));
        if (!(a == a)) a = 3.0e38f;
        mx = fmaxf(mx, a);
    }
#pragma unroll
    for (int s = 32; s >= 1; s >>= 1) mx = fmaxf(mx, __shfl_xor(mx, s));
    return (mx > 1.0e6f) ? 1 : 0;
}

// ---------------- K1: prep — cnorm + folded weights + small-table products -
// bi 0..499: cnorm | 500..627: BabT | 628..755: BfgT | 756: vA | 757: vF
// 758..857: PA_ut | 858..869: PA_ha | 870..969: PF_it
__global__ __launch_bounds__(128) void k_prep(
    const void* Eq, const void* Wf, const void* Wa, const void* Wg,
    const void* bfu, const void* ba, const void* bg,
    const void* Eut, const void* Eha, const void* Eit, const void* Ec,
    float* cnorm, float* BabT, float* BfgT,
    float* vA0, float* vA1, float* vF0, float* vF1,
    float* PA_ut, float* PA_ha, float* PF_it) {
    const int m = detect_mode(Eq);
    const int bi = blockIdx.x, tid = threadIdx.x;
    __shared__ float cs2s[128];
    __shared__ float tmp[2];
    if (bi < 500) {
        const int c = bi;
        float v = ldf(Ec, c * 128 + tid, m);
        float s = wave_red(v * v);
        if ((tid & 63) == 0) tmp[tid >> 6] = s;
        __syncthreads();
        if (tid == 0) cnorm[c] = fmaxf(sqrtf(tmp[0] + tmp[1]), 1e-8f);
    } else if (bi < 628) {
        const int r = bi - 500;
        float acc = 0.f;
        for (int j = 0; j < 128; ++j)
            acc += ldf(Wf, r * 128 + j, m) * ldf(Wa, j * 128 + tid, m);
        BabT[r * 128 + tid] = acc;
    } else if (bi < 756) {
        const int r = bi - 628;
        float acc = 0.f;
        for (int j = 0; j < 128; ++j)
            acc += ldf(Wf, r * 128 + j, m) * ldf(Wg, (256 + j) * 128 + tid, m);
        BfgT[r * 128 + tid] = acc;
    } else if (bi == 756) {
        float s = 0.f;
        for (int r = 0; r < 128; ++r) s += ldf(Wf, (128 + r) * 128 + tid, m);
        cs2s[tid] = s;
        __syncthreads();
        float a0 = 0.f, a1 = 0.f;
        for (int j = 0; j < 128; ++j) {
            float wv = ldf(Wa, j * 128 + tid, m);
            a0 += ldf(bfu, j, m) * wv;
            a1 += cs2s[j] * wv;
        }
        vA0[tid] = a0 + ldf(ba, tid, m);
        vA1[tid] = a1;
    } else if (bi == 757) {
        float s = 0.f;
        for (int r = 0; r < 128; ++r) s += ldf(Wf, (128 + r) * 128 + tid, m);
        cs2s[tid] = s;
        __syncthreads();
        float a0 = 0.f, a1 = 0.f;
        for (int j = 0; j < 128; ++j) {
            float wv = ldf(Wg, (256 + j) * 128 + tid, m);
            a0 += ldf(bfu, j, m) * wv;
            a1 += cs2s[j] * wv;
        }
        vF0[tid] = a0 + ldf(bg, tid, m);
        vF1[tid] = a1;
    } else if (bi < 858) {
        const int r = bi - 758;  // PA_ut
        float acc = 0.f;
        for (int j = 0; j < 128; ++j)
            acc += ldf(Eut, r * 128 + j, m) * ldf(Wa, (128 + j) * 128 + tid, m);
        PA_ut[r * 128 + tid] = acc;
    } else if (bi < 870) {
        const int r = bi - 858;  // PA_ha
        float acc = 0.f;
        for (int j = 0; j < 128; ++j)
            acc += ldf(Eha, r * 128 + j, m) * ldf(Wa, (256 + j) * 128 + tid, m);
        PA_ha[r * 128 + tid] = acc;
    } else {
        const int r = bi - 870;  // PF_it
        float acc = 0.f;
        for (int j = 0; j < 128; ++j)
            acc += ldf(Eit, r * 128 + j, m) * ldf(Wg, (128 + j) * 128 + tid, m);
        PF_it[r * 128 + tid] = acc;
    }
}

// ---------------- K2: mid — per-question GEMM (bi<157) + p2q (bi>=157) -----
__global__ __launch_bounds__(256) void k_mid(
    const void* Eq, const void* Eqd, const void* Ec,
    const int* q2c, const int* q2cm,
    const float* BabT, const float* BfgT, const float* cnorm,
    float* PA_q, float* PF_q, float* qdm, float* qd10) {
    const int m = detect_mode(Eq);
    const int tid = threadIdx.x;
    const int bi = blockIdx.x;
    if (bi < 157) {
        __shared__ float At[64][36];
        __shared__ float Bt0[32][128];
        __shared__ float Bt1[32][128];
        const int r0 = bi * 64;
        float acc0[4][8], acc1[4][8];
#pragma unroll
        for (int j = 0; j < 4; ++j)
#pragma unroll
            for (int i = 0; i < 8; ++i) { acc0[j][i] = 0.f; acc1[j][i] = 0.f; }
        const int tx = tid & 15, ty = tid >> 4;
        for (int ks = 0; ks < 4; ++ks) {
            {   // A tile: 64 rows x 32 k from Eq
                const int row = tid >> 2, seg = tid & 3;
                const int q = clampi(r0 + row, 0, NQq - 1);
                const int ei = q * 128 + ks * 32 + seg * 8;
                float* dst = &At[row][seg * 8];
                if (m) {
                    const float4* src = (const float4*)((const float*)Eq + ei);
                    float4 v0 = src[0], v1 = src[1];
                    dst[0] = v0.x; dst[1] = v0.y; dst[2] = v0.z; dst[3] = v0.w;
                    dst[4] = v1.x; dst[5] = v1.y; dst[6] = v1.z; dst[7] = v1.w;
                } else {
                    uint4 v = *(const uint4*)((const u16*)Eq + ei);
                    dst[0] = bf2f((u16)(v.x & 0xffff)); dst[1] = bf2f((u16)(v.x >> 16));
                    dst[2] = bf2f((u16)(v.y & 0xffff)); dst[3] = bf2f((u16)(v.y >> 16));
                    dst[4] = bf2f((u16)(v.z & 0xffff)); dst[5] = bf2f((u16)(v.z >> 16));
                    dst[6] = bf2f((u16)(v.w & 0xffff)); dst[7] = bf2f((u16)(v.w >> 16));
                }
            }
            {   // B tiles
                const float4* s0 = (const float4*)(BabT + ks * 32 * 128);
                const float4* s1 = (const float4*)(BfgT + ks * 32 * 128);
                float4* d0 = (float4*)&Bt0[0][0];
                float4* d1 = (float4*)&Bt1[0][0];
#pragma unroll
                for (int k = 0; k < 4; ++k) {
                    d0[tid + k * 256] = s0[tid + k * 256];
                    d1[tid + k * 256] = s1[tid + k * 256];
                }
            }
            __syncthreads();
#pragma unroll
            for (int kk = 0; kk < 32; kk += 4) {
                float a_[4][4];
                *(float4*)&a_[0][0] = *(const float4*)&At[ty * 4 + 0][kk];
                *(float4*)&a_[1][0] = *(const float4*)&At[ty * 4 + 1][kk];
                *(float4*)&a_[2][0] = *(const float4*)&At[ty * 4 + 2][kk];
                *(float4*)&a_[3][0] = *(const float4*)&At[ty * 4 + 3][kk];
#pragma unroll
                for (int q = 0; q < 4; ++q) {
                    float4 b0 = *(const float4*)&Bt0[kk + q][tx * 8];
                    float4 b1 = *(const float4*)&Bt0[kk + q][tx * 8 + 4];
                    float4 c0 = *(const float4*)&Bt1[kk + q][tx * 8];
                    float4 c1 = *(const float4*)&Bt1[kk + q][tx * 8 + 4];
#pragma unroll
                    for (int j = 0; j < 4; ++j) {
                        const float av = a_[j][q];
                        acc0[j][0] += av * b0.x; acc0[j][1] += av * b0.y;
                        acc0[j][2] += av * b0.z; acc0[j][3] += av * b0.w;
                        acc0[j][4] += av * b1.x; acc0[j][5] += av * b1.y;
                        acc0[j][6] += av * b1.z; acc0[j][7] += av * b1.w;
                        acc1[j][0] += av * c0.x; acc1[j][1] += av * c0.y;
                        acc1[j][2] += av * c0.z; acc1[j][3] += av * c0.w;
                        acc1[j][4] += av * c1.x; acc1[j][5] += av * c1.y;
                        acc1[j][6] += av * c1.z; acc1[j][7] += av * c1.w;
                    }
                }
            }
            __syncthreads();
        }
#pragma unroll
        for (int j = 0; j < 4; ++j) {
            const int q = r0 + ty * 4 + j;
            if (q < NQq) {
                float* oa = PA_q + q * 128 + tx * 8;
                float* of = PF_q + q * 128 + tx * 8;
#pragma unroll
                for (int i = 0; i < 8; ++i) { oa[i] = acc0[j][i]; of[i] = acc1[j][i]; }
            }
        }
    } else {
        // p2q: per-question qdm + qd10
        const int wv = tid >> 6, lane = tid & 63;
        const int q = (bi - 157) * 4 + wv;  // 2500*4 == 10000
        const float qa = ldf(Eq, q * 128 + lane, m);
        const float qb = ldf(Eq, q * 128 + 64 + lane, m);
        const float nqc = fmaxf(sqrtf(wave_red(qa * qa + qb * qb)), 1e-8f);
        const int4 cc = ((const int4*)q2c)[q];
        const int4 mm = ((const int4*)q2cm)[q];
        const int cks[4] = {clampi(cc.x, 0, NCc - 1), clampi(cc.y, 0, NCc - 1),
                            clampi(cc.z, 0, NCc - 1), clampi(cc.w, 0, NCc - 1)};
        const int ms[4]  = {mm.x, mm.y, mm.z, mm.w};
        float qs = 0.f;
#pragma unroll
        for (int k = 0; k < 4; ++k) {
            const int ck = cks[k];
            float dot = wave_red(qa * ldf(Ec, ck * 128 + lane, m) +
                                 qb * ldf(Ec, ck * 128 + 64 + lane, m));
            qs += (float)ms[k] * (0.5f * dot / (nqc * cnorm[ck]) + 0.5f);
        }
        if (lane == 0) {
            qdm[q] = qs;
            qd10[q] = 10.f / (1.f + __expf(-ldf(Eqd, q, m)));
        }
    }
}

// ---------------- K3: scan — wave-owned state, ONE barrier per step --------
// Wave w owns index range I_w=[32w,32w+32) for BOTH the matvec i-input and
// the lc[d] state: lp[I_w] is written and read only by wave w (no barrier,
// compiler lgkmcnt handles it). Cross-wave traffic = part[4][128] only,
// parity double-buffered => 1 __syncthreads per step.
__global__ __launch_bounds__(256) void p4_scan(
    const int* q_seq, const int* ut_seq, const int* ha_seq, const int* it_seq,
    const int* c_seq,
    const void* Eq, const void* Wg, const void* L0,
    const float* PA_q, const float* PA_ut, const float* PA_ha,
    const float* PF_q, const float* PF_it,
    const float* vA0, const float* vA1, const float* vF0, const float* vF1,
    float* lc_seq) {
    const int m = detect_mode(Eq);
    const int b = blockIdx.x;
    const int tid = threadIdx.x;
    const int wv = tid >> 6, l = tid & 63;
    const int d0 = 2 * l;              // partial-column pair owned in phase A
    const int ib = wv << 5;            // wave's i-range base
    const int dd = ib + (l & 31);      // owned state index (2 lanes redundant)

    __shared__ float lp_sh[128];
    __shared__ float part[2][4][128];
    __shared__ float st_ab[CHK * 128];
    __shared__ float st_pf[CHK * 128];

    float wA[32], wB[32];
#pragma unroll
    for (int k = 0; k < 32; ++k) {
        wA[k] = ldf(Wg, (ib + k) * 128 + d0, m);
        wB[k] = ldf(Wg, (ib + k) * 128 + d0 + 1, m);
    }
    float lc = ldf(L0, b * 128 + dd, m);
    if (l < 32) lp_sh[dd] = lc;

    // staging role: thread -> (row srow in chunk, 8-float segment seg)
    const int srow = tid >> 4, seg = tid & 15;
    const int off8 = seg * 8;
    const float4 A0a = *(const float4*)(vA0 + off8), A0b = *(const float4*)(vA0 + off8 + 4);
    const float4 A1a = *(const float4*)(vA1 + off8), A1b = *(const float4*)(vA1 + off8 + 4);
    const float4 F0a = *(const float4*)(vF0 + off8), F0b = *(const float4*)(vF0 + off8 + 4);
    const float4 F1a = *(const float4*)(vF1 + off8), F1b = *(const float4*)(vF1 + off8 + 4);

    float4 qa0, qa1, ua0, ua1, ga0, ga1, qf0, qf1, if0, if1;
    float cf;
#define LOAD_CHUNK(C)                                                          \
    {                                                                          \
        int tt = (C) * CHK + srow; if (tt > Tt - 1) tt = Tt - 1;               \
        const int base = b * Ss + tt;                                          \
        const int qt = clampi(q_seq[base], 0, NQq - 1);                        \
        const int ut = clampi(ut_seq[base], 0, 99);                            \
        const int ha = clampi(ha_seq[base], 0, 11);                            \
        const int it = clampi(it_seq[base], 0, 99);                            \
        cf = (float)c_seq[base];                                               \
        const float* pq = PA_q + qt * 128 + off8;                              \
        qa0 = *(const float4*)pq; qa1 = *(const float4*)(pq + 4);              \
        const float* pu = PA_ut + ut * 128 + off8;                             \
        ua0 = *(const float4*)pu; ua1 = *(const float4*)(pu + 4);              \
        const float* ph = PA_ha + ha * 128 + off8;                             \
        ga0 = *(const float4*)ph; ga1 = *(const float4*)(ph + 4);              \
        const float* pf = PF_q + qt * 128 + off8;                              \
        qf0 = *(const float4*)pf; qf1 = *(const float4*)(pf + 4);              \
        const float* pi = PF_it + it * 128 + off8;                             \
        if0 = *(const float4*)pi; if1 = *(const float4*)(pi + 4);              \
    }

    LOAD_CHUNK(0)
    float lcbuf[CHK];
    int par = 0;

    for (int c = 0; c < NCH; ++c) {
        __syncthreads();   // prior chunk's st readers done (and lp init at c=0)
        {   // publish staged chunk c
            float4 ab0 = f4fma(cf, A1a, f4add(f4add(qa0, ua0), f4add(ga0, A0a)));
            float4 ab1 = f4fma(cf, A1b, f4add(f4add(qa1, ua1), f4add(ga1, A0b)));
            float4 pf0 = f4fma(cf, F1a, f4add(qf0, f4add(if0, F0a)));
            float4 pf1 = f4fma(cf, F1b, f4add(qf1, f4add(if1, F0b)));
            float4* sa = (float4*)(st_ab + srow * 128 + off8);
            sa[0] = ab0; sa[1] = ab1;
            float4* sp = (float4*)(st_pf + srow * 128 + off8);
            sp[0] = pf0; sp[1] = pf1;
        }
        if (c + 1 < NCH) LOAD_CHUNK(c + 1)
        __syncthreads();   // st visible

#pragma unroll
        for (int s = 0; s < CHK; ++s) {
            // phase A: partial matvec over own i-range (uniform broadcasts)
            const float4* lp4 = (const float4*)(lp_sh + ib);
            float pa = 0.f, pb = 0.f;
#pragma unroll
            for (int k = 0; k < 8; ++k) {
                float4 v = lp4[k];
                pa += v.x * wA[4 * k] + v.y * wA[4 * k + 1]
                    + v.z * wA[4 * k + 2] + v.w * wA[4 * k + 3];
                pb += v.x * wB[4 * k] + v.y * wB[4 * k + 1]
                    + v.z * wB[4 * k + 2] + v.w * wB[4 * k + 3];
            }
            *(float2*)&part[par][wv][d0] = make_float2(pa, pb);
            __syncthreads();   // the ONLY per-step barrier
            // phase B: reduce partials for owned index dd, update state
            const float fs = part[par][0][dd] + part[par][1][dd]
                           + part[par][2][dd] + part[par][3][dd];
            const float ab = st_ab[(s << 7) + dd];
            const float pf = st_pf[(s << 7) + dd];
            const float fg = 1.f / (1.f + __expf(-(fs + pf)));
            lc = lc * fg + ab;
            if (l < 32) lp_sh[dd] = lc;   // own range; own wave reads next step
            lcbuf[s] = lc;
            par ^= 1;
        }
        // flush lc history for chunk c (no sync needed; global stores)
        if (l < 32) {
#pragma unroll
            for (int s = 0; s < CHK; ++s) {
                const int t = c * CHK + s;
                if (t < Tt)
                    lc_seq[((long)t * 128 + b) * 128 + dd] = lcbuf[s];
            }
        }
    }
#undef LOAD_CHUNK
}

// ---------------- K4: parallel cosine/logit epilogue (one wave per row) ----
__global__ __launch_bounds__(256) void p5_out(
    const int* q_seq, const int* q2c, const int* q2cm,
    const float* lc_seq, const float* qdm, const float* qd10,
    const float* cnorm, const void* Eq, const void* Ec, void* out) {
    const int m = detect_mode(Eq);
    const int wv = threadIdx.x >> 6, lane = threadIdx.x & 63;
    const int r = blockIdx.x * 4 + wv;  // 6368*4 == 25472 == Tt*Bb
    const int t = r >> 7, b = r & 127;
    const int qt  = clampi(q_seq[b * Ss + t], 0, NQq - 1);
    const int qt1 = clampi(q_seq[b * Ss + t + 1], 0, NQq - 1);
    const int4 mm = ((const int4*)q2cm)[qt];
    int4 ci = ((const int4*)q2c)[qt1];
    const int c0 = clampi(ci.x, 0, NCc - 1), c1 = clampi(ci.y, 0, NCc - 1);
    const int c2 = clampi(ci.z, 0, NCc - 1), c3 = clampi(ci.w, 0, NCc - 1);
    const float la = lc_seq[(long)r * 128 + lane];
    const float lb = lc_seq[(long)r * 128 + 64 + lane];
    float nl = la * la + lb * lb;
    float d0 = la * ldf(Ec, c0 * 128 + lane, m) + lb * ldf(Ec, c0 * 128 + 64 + lane, m);
    float d1 = la * ldf(Ec, c1 * 128 + lane, m) + lb * ldf(Ec, c1 * 128 + 64 + lane, m);
    float d2 = la * ldf(Ec, c2 * 128 + lane, m) + lb * ldf(Ec, c2 * 128 + 64 + lane, m);
    float d3 = la * ldf(Ec, c3 * 128 + lane, m) + lb * ldf(Ec, c3 * 128 + 64 + lane, m);
#pragma unroll
    for (int s = 32; s >= 1; s >>= 1) {
        nl += __shfl_xor(nl, s);
        d0 += __shfl_xor(d0, s); d1 += __shfl_xor(d1, s);
        d2 += __shfl_xor(d2, s); d3 += __shfl_xor(d3, s);
    }
    if (lane == 0) {
        const float inl = 1.f / fmaxf(sqrtf(nl), 1e-8f);
        const float accv = (float)mm.x * (0.5f * d0 * inl / cnorm[c0] + 0.5f)
                         + (float)mm.y * (0.5f * d1 * inl / cnorm[c1] + 0.5f)
                         + (float)mm.z * (0.5f * d2 * inl / cnorm[c2] + 0.5f)
                         + (float)mm.w * (0.5f * d3 * inl / cnorm[c3] + 0.5f);
        const float logit = qd10[qt1] * (accv - qdm[qt]);
        stf(out, b * Ss + t, m, 1.f / (1.f + __expf(-logit)));
        if (t == 0) stf(out, b * Ss + 199, m, 0.f);
    }
}

extern "C" void kernel_launch(void* const* d_in, const int* in_sizes, int n_in,
                              void* d_out, int out_size, void* d_ws, size_t ws_size,
                              hipStream_t stream) {
    (void)in_sizes; (void)n_in; (void)out_size; (void)ws_size;
    const int* q_seq  = (const int*)d_in[0];
    const int* ha_seq = (const int*)d_in[1];
    const int* c_seq  = (const int*)d_in[2];
    const int* it_seq = (const int*)d_in[3];
    const int* ut_seq = (const int*)d_in[4];
    const int* q2c    = (const int*)d_in[5];
    const int* q2cm   = (const int*)d_in[6];
    const void* Eq   = d_in[7];
    const void* Eqd  = d_in[8];
    const void* Ec   = d_in[9];
    const void* Eit  = d_in[10];
    const void* Eut  = d_in[11];
    const void* Eha  = d_in[12];
    const void* Wf   = d_in[13];
    const void* bfu  = d_in[14];
    const void* Wa   = d_in[15];
    const void* ba   = d_in[16];
    const void* Wg   = d_in[17];
    const void* bg   = d_in[18];
    const void* L0   = d_in[19];

    // workspace layout (floats) — ~23.5 MB
    float* cnorm = (float*)d_ws;                // 512 (500 used)
    float* vA0   = cnorm + 512;                 // 128 x4
    float* vA1   = vA0 + 128;
    float* vF0   = vA1 + 128;
    float* vF1   = vF0 + 128;
    float* BabT  = vF1 + 128;                   // 16384
    float* BfgT  = BabT + 16384;                // 16384
    float* PA_ut = BfgT + 16384;                // 12800
    float* PA_ha = PA_ut + 12800;               // 1536
    float* PF_it = PA_ha + 1536;                // 12800
    float* qdm   = PF_it + 12800;               // 10016
    float* qd10  = qdm + 10016;                 // 10016
    float* PA_q  = qd10 + 10016;                // 1,280,000
    float* PF_q  = PA_q + 1280000;              // 1,280,000
    float* lc_seq= PF_q + 1280000;              // 3,260,416

    hipLaunchKernelGGL(k_prep, dim3(970), dim3(128), 0, stream,
                       Eq, Wf, Wa, Wg, bfu, ba, bg, Eut, Eha, Eit, Ec,
                       cnorm, BabT, BfgT, vA0, vA1, vF0, vF1, PA_ut, PA_ha, PF_it);
    hipLaunchKernelGGL(k_mid, dim3(2657), dim3(256), 0, stream,
                       Eq, Eqd, Ec, q2c, q2cm, BabT, BfgT, cnorm,
                       PA_q, PF_q, qdm, qd10);
    hipLaunchKernelGGL(p4_scan, dim3(Bb), dim3(256), 0, stream,
                       q_seq, ut_seq, ha_seq, it_seq, c_seq, Eq, Wg, L0,
                       PA_q, PA_ut, PA_ha, PF_q, PF_it,
                       vA0, vA1, vF0, vF1, lc_seq);
    hipLaunchKernelGGL(p5_out, dim3(Tt * Bb / 4), dim3(256), 0, stream,
                       q_seq, q2c, q2cm, lc_seq, qdm, qd10, cnorm, Eq, Ec, d_out);
}

// Round 8
// 235.393 us; speedup vs baseline: 2.1270x; 1.0988x over previous
//
#include <hip/hip_runtime.h>
#include <hip/hip_bf16.h>

typedef unsigned short u16;

#define Bb  128
#define Ss  200
#define Tt  199   // S-1
#define Dd  128
#define Kk  4
#define NQq 10000
#define NCc 500
#define CHK 16    // scan chunk (steps staged per refill)
#define NCH 13    // ceil(199/16)

__device__ inline float bf2f(u16 u) {
    union { unsigned int i; float f; } x;
    x.i = ((unsigned int)u) << 16;
    return x.f;
}

// mode m: 1 = buffers hold fp32, 0 = buffers hold bf16
__device__ inline float ldf(const void* p, int i, int m) {
    if (m) return ((const float*)p)[i];
    return bf2f(((const u16*)p)[i]);
}

__device__ inline void stf(void* p, int i, int m, float v) {
    if (m) ((float*)p)[i] = v;
    else ((__hip_bfloat16*)p)[i] = __float2bfloat16(v);
}

__device__ inline int clampi(int v, int lo, int hi) {
    return v < lo ? lo : (v > hi ? hi : v);
}

__device__ inline float wave_red(float v) {
#pragma unroll
    for (int m = 32; m >= 1; m >>= 1) v += __shfl_xor(v, m);
    return v;
}

__device__ inline float4 f4add(float4 a, float4 b) {
    return make_float4(a.x + b.x, a.y + b.y, a.z + b.z, a.w + b.w);
}
__device__ inline float4 f4fma(float s, float4 a, float4 b) {
    return make_float4(fmaf(s, a.x, b.x), fmaf(s, a.y, b.y),
                       fmaf(s, a.z, b.z), fmaf(s, a.w, b.w));
}

// per-block inline dtype detection: scan first 256 u16 of Eq as bf16.
// fp32 data reinterpreted as bf16 shows huge/NaN values w.p. 1-1e-31.
__device__ inline int detect_mode(const void* Eq) {
    const u16* q = (const u16*)Eq;
    const int l = threadIdx.x & 63;
    float mx = 0.f;
#pragma unroll
    for (int k = 0; k < 4; ++k) {
        float a = fabsf(bf2f(q[l * 4 + k]));
        if (!(a == a)) a = 3.0e38f;
        mx = fmaxf(mx, a);
    }
#pragma unroll
    for (int s = 32; s >= 1; s >>= 1) mx = fmaxf(mx, __shfl_xor(mx, s));
    return (mx > 1.0e6f) ? 1 : 0;
}

// ---------------- K1: prep — cnorm + folded weights + small-table products -
// bi 0..499: cnorm | 500..627: BabT | 628..755: BfgT | 756: vA | 757: vF
// 758..857: PA_ut | 858..869: PA_ha | 870..969: PF_it
__global__ __launch_bounds__(128) void k_prep(
    const void* Eq, const void* Wf, const void* Wa, const void* Wg,
    const void* bfu, const void* ba, const void* bg,
    const void* Eut, const void* Eha, const void* Eit, const void* Ec,
    float* cnorm, float* BabT, float* BfgT,
    float* vA0, float* vA1, float* vF0, float* vF1,
    float* PA_ut, float* PA_ha, float* PF_it) {
    const int m = detect_mode(Eq);
    const int bi = blockIdx.x, tid = threadIdx.x;
    __shared__ float cs2s[128];
    __shared__ float tmp[2];
    if (bi < 500) {
        const int c = bi;
        float v = ldf(Ec, c * 128 + tid, m);
        float s = wave_red(v * v);
        if ((tid & 63) == 0) tmp[tid >> 6] = s;
        __syncthreads();
        if (tid == 0) cnorm[c] = fmaxf(sqrtf(tmp[0] + tmp[1]), 1e-8f);
    } else if (bi < 628) {
        const int r = bi - 500;
        float acc = 0.f;
        for (int j = 0; j < 128; ++j)
            acc += ldf(Wf, r * 128 + j, m) * ldf(Wa, j * 128 + tid, m);
        BabT[r * 128 + tid] = acc;
    } else if (bi < 756) {
        const int r = bi - 628;
        float acc = 0.f;
        for (int j = 0; j < 128; ++j)
            acc += ldf(Wf, r * 128 + j, m) * ldf(Wg, (256 + j) * 128 + tid, m);
        BfgT[r * 128 + tid] = acc;
    } else if (bi == 756) {
        float s = 0.f;
        for (int r = 0; r < 128; ++r) s += ldf(Wf, (128 + r) * 128 + tid, m);
        cs2s[tid] = s;
        __syncthreads();
        float a0 = 0.f, a1 = 0.f;
        for (int j = 0; j < 128; ++j) {
            float wv = ldf(Wa, j * 128 + tid, m);
            a0 += ldf(bfu, j, m) * wv;
            a1 += cs2s[j] * wv;
        }
        vA0[tid] = a0 + ldf(ba, tid, m);
        vA1[tid] = a1;
    } else if (bi == 757) {
        float s = 0.f;
        for (int r = 0; r < 128; ++r) s += ldf(Wf, (128 + r) * 128 + tid, m);
        cs2s[tid] = s;
        __syncthreads();
        float a0 = 0.f, a1 = 0.f;
        for (int j = 0; j < 128; ++j) {
            float wv = ldf(Wg, (256 + j) * 128 + tid, m);
            a0 += ldf(bfu, j, m) * wv;
            a1 += cs2s[j] * wv;
        }
        vF0[tid] = a0 + ldf(bg, tid, m);
        vF1[tid] = a1;
    } else if (bi < 858) {
        const int r = bi - 758;  // PA_ut
        float acc = 0.f;
        for (int j = 0; j < 128; ++j)
            acc += ldf(Eut, r * 128 + j, m) * ldf(Wa, (128 + j) * 128 + tid, m);
        PA_ut[r * 128 + tid] = acc;
    } else if (bi < 870) {
        const int r = bi - 858;  // PA_ha
        float acc = 0.f;
        for (int j = 0; j < 128; ++j)
            acc += ldf(Eha, r * 128 + j, m) * ldf(Wa, (256 + j) * 128 + tid, m);
        PA_ha[r * 128 + tid] = acc;
    } else {
        const int r = bi - 870;  // PF_it
        float acc = 0.f;
        for (int j = 0; j < 128; ++j)
            acc += ldf(Eit, r * 128 + j, m) * ldf(Wg, (128 + j) * 128 + tid, m);
        PF_it[r * 128 + tid] = acc;
    }
}

// ---------------- K2: mid — per-question GEMM (bi<313) + p2q (bi>=313) -----
// GEMM tiles are 32 rows x 128 cols x both matrices (313 blocks for 2x the
// occupancy of the old 64-row/157-block split).
__global__ __launch_bounds__(256) void k_mid(
    const void* Eq, const void* Eqd, const void* Ec,
    const int* q2c, const int* q2cm,
    const float* BabT, const float* BfgT, const float* cnorm,
    float* PA_q, float* PF_q, float* qdm, float* qd10) {
    const int m = detect_mode(Eq);
    const int tid = threadIdx.x;
    const int bi = blockIdx.x;
    if (bi < 313) {
        __shared__ float At[32][36];
        __shared__ float Bt0[32][128];
        __shared__ float Bt1[32][128];
        const int r0 = bi * 32;
        float acc0[2][8], acc1[2][8];
#pragma unroll
        for (int j = 0; j < 2; ++j)
#pragma unroll
            for (int i = 0; i < 8; ++i) { acc0[j][i] = 0.f; acc1[j][i] = 0.f; }
        const int tx = tid & 15, ty = tid >> 4;
        for (int ks = 0; ks < 4; ++ks) {
            {   // A tile: 32 rows x 32 k from Eq; 4 elements/thread
                const int row = tid >> 3, seg = tid & 7;
                const int q = clampi(r0 + row, 0, NQq - 1);
                const int ei = q * 128 + ks * 32 + seg * 4;
                float* dst = &At[row][seg * 4];
                if (m) {
                    float4 v = *(const float4*)((const float*)Eq + ei);
                    dst[0] = v.x; dst[1] = v.y; dst[2] = v.z; dst[3] = v.w;
                } else {
                    uint2 v = *(const uint2*)((const u16*)Eq + ei);
                    dst[0] = bf2f((u16)(v.x & 0xffff)); dst[1] = bf2f((u16)(v.x >> 16));
                    dst[2] = bf2f((u16)(v.y & 0xffff)); dst[3] = bf2f((u16)(v.y >> 16));
                }
            }
            {   // B tiles
                const float4* s0 = (const float4*)(BabT + ks * 32 * 128);
                const float4* s1 = (const float4*)(BfgT + ks * 32 * 128);
                float4* d0 = (float4*)&Bt0[0][0];
                float4* d1 = (float4*)&Bt1[0][0];
#pragma unroll
                for (int k = 0; k < 4; ++k) {
                    d0[tid + k * 256] = s0[tid + k * 256];
                    d1[tid + k * 256] = s1[tid + k * 256];
                }
            }
            __syncthreads();
#pragma unroll
            for (int kk = 0; kk < 32; kk += 4) {
                float a_[2][4];
                *(float4*)&a_[0][0] = *(const float4*)&At[ty * 2 + 0][kk];
                *(float4*)&a_[1][0] = *(const float4*)&At[ty * 2 + 1][kk];
#pragma unroll
                for (int q = 0; q < 4; ++q) {
                    float4 b0 = *(const float4*)&Bt0[kk + q][tx * 8];
                    float4 b1 = *(const float4*)&Bt0[kk + q][tx * 8 + 4];
                    float4 c0 = *(const float4*)&Bt1[kk + q][tx * 8];
                    float4 c1 = *(const float4*)&Bt1[kk + q][tx * 8 + 4];
#pragma unroll
                    for (int j = 0; j < 2; ++j) {
                        const float av = a_[j][q];
                        acc0[j][0] += av * b0.x; acc0[j][1] += av * b0.y;
                        acc0[j][2] += av * b0.z; acc0[j][3] += av * b0.w;
                        acc0[j][4] += av * b1.x; acc0[j][5] += av * b1.y;
                        acc0[j][6] += av * b1.z; acc0[j][7] += av * b1.w;
                        acc1[j][0] += av * c0.x; acc1[j][1] += av * c0.y;
                        acc1[j][2] += av * c0.z; acc1[j][3] += av * c0.w;
                        acc1[j][4] += av * c1.x; acc1[j][5] += av * c1.y;
                        acc1[j][6] += av * c1.z; acc1[j][7] += av * c1.w;
                    }
                }
            }
            __syncthreads();
        }
#pragma unroll
        for (int j = 0; j < 2; ++j) {
            const int q = r0 + ty * 2 + j;
            if (q < NQq) {
                float* oa = PA_q + q * 128 + tx * 8;
                float* of = PF_q + q * 128 + tx * 8;
#pragma unroll
                for (int i = 0; i < 8; ++i) { oa[i] = acc0[j][i]; of[i] = acc1[j][i]; }
            }
        }
    } else {
        // p2q: per-question qdm + qd10
        const int wv = tid >> 6, lane = tid & 63;
        const int q = (bi - 313) * 4 + wv;  // 2500*4 == 10000
        const float qa = ldf(Eq, q * 128 + lane, m);
        const float qb = ldf(Eq, q * 128 + 64 + lane, m);
        const float nqc = fmaxf(sqrtf(wave_red(qa * qa + qb * qb)), 1e-8f);
        const int4 cc = ((const int4*)q2c)[q];
        const int4 mm = ((const int4*)q2cm)[q];
        const int cks[4] = {clampi(cc.x, 0, NCc - 1), clampi(cc.y, 0, NCc - 1),
                            clampi(cc.z, 0, NCc - 1), clampi(cc.w, 0, NCc - 1)};
        const int ms[4]  = {mm.x, mm.y, mm.z, mm.w};
        float qs = 0.f;
#pragma unroll
        for (int k = 0; k < 4; ++k) {
            const int ck = cks[k];
            float dot = wave_red(qa * ldf(Ec, ck * 128 + lane, m) +
                                 qb * ldf(Ec, ck * 128 + 64 + lane, m));
            qs += (float)ms[k] * (0.5f * dot / (nqc * cnorm[ck]) + 0.5f);
        }
        if (lane == 0) {
            qdm[q] = qs;
            qd10[q] = 10.f / (1.f + __expf(-ldf(Eqd, q, m)));
        }
    }
}

// ---------------- K3: scan — readlane matvec, 1 barrier, minimal DS --------
// Wave w owns i-range AND state lc[32w..32w+32) (lane l<32 holds lc[32w+l]).
// The matvec's lp inputs for wave w are ITS OWN lanes' lc registers —
// broadcast via v_readlane (VALU, no LDS pipe, no LDS latency). Per-step DS
// ops: part write (b64) + part reads + st reads ≈ 14 wave-inst (was ~56).
__global__ __launch_bounds__(256) void p4_scan(
    const int* q_seq, const int* ut_seq, const int* ha_seq, const int* it_seq,
    const int* c_seq,
    const void* Eq, const void* Wg, const void* L0,
    const float* PA_q, const float* PA_ut, const float* PA_ha,
    const float* PF_q, const float* PF_it,
    const float* vA0, const float* vA1, const float* vF0, const float* vF1,
    float* lc_seq) {
    const int m = detect_mode(Eq);
    const int b = blockIdx.x;
    const int tid = threadIdx.x;
    const int wv = tid >> 6, l = tid & 63;
    const int d0 = 2 * l;              // partial-column pair computed in phase A
    const int ib = wv << 5;            // wave's i-range / state base
    const int dd = ib + (l & 31);      // owned state index (lanes<32)

    __shared__ float part[2][4][128];
    __shared__ float st_ab[CHK * 128];
    __shared__ float st_pf[CHK * 128];

    float wA[32], wB[32];
#pragma unroll
    for (int k = 0; k < 32; ++k) {
        wA[k] = ldf(Wg, (ib + k) * 128 + d0, m);
        wB[k] = ldf(Wg, (ib + k) * 128 + d0 + 1, m);
    }
    float lc = (l < 32) ? ldf(L0, b * 128 + dd, m) : 0.f;

    // staging role: thread -> (row srow in chunk, 8-float segment seg)
    const int srow = tid >> 4, seg = tid & 15;
    const int off8 = seg * 8;
    const float4 A0a = *(const float4*)(vA0 + off8), A0b = *(const float4*)(vA0 + off8 + 4);
    const float4 A1a = *(const float4*)(vA1 + off8), A1b = *(const float4*)(vA1 + off8 + 4);
    const float4 F0a = *(const float4*)(vF0 + off8), F0b = *(const float4*)(vF0 + off8 + 4);
    const float4 F1a = *(const float4*)(vF1 + off8), F1b = *(const float4*)(vF1 + off8 + 4);

    float4 qa0, qa1, ua0, ua1, ga0, ga1, qf0, qf1, if0, if1;
    float cf;
#define LOAD_CHUNK(C)                                                          \
    {                                                                          \
        int tt = (C) * CHK + srow; if (tt > Tt - 1) tt = Tt - 1;               \
        const int base = b * Ss + tt;                                          \
        const int qt = clampi(q_seq[base], 0, NQq - 1);                        \
        const int ut = clampi(ut_seq[base], 0, 99);                            \
        const int ha = clampi(ha_seq[base], 0, 11);                            \
        const int it = clampi(it_seq[base], 0, 99);                            \
        cf = (float)c_seq[base];                                               \
        const float* pq = PA_q + qt * 128 + off8;                              \
        qa0 = *(const float4*)pq; qa1 = *(const float4*)(pq + 4);              \
        const float* pu = PA_ut + ut * 128 + off8;                             \
        ua0 = *(const float4*)pu; ua1 = *(const float4*)(pu + 4);              \
        const float* ph = PA_ha + ha * 128 + off8;                             \
        ga0 = *(const float4*)ph; ga1 = *(const float4*)(ph + 4);              \
        const float* pf = PF_q + qt * 128 + off8;                              \
        qf0 = *(const float4*)pf; qf1 = *(const float4*)(pf + 4);              \
        const float* pi = PF_it + it * 128 + off8;                             \
        if0 = *(const float4*)pi; if1 = *(const float4*)(pi + 4);              \
    }

    LOAD_CHUNK(0)
    float lcbuf[CHK];
    int par = 0;

    for (int c = 0; c < NCH; ++c) {
        __syncthreads();   // prior chunk's st readers done
        {   // publish staged chunk c
            float4 ab0 = f4fma(cf, A1a, f4add(f4add(qa0, ua0), f4add(ga0, A0a)));
            float4 ab1 = f4fma(cf, A1b, f4add(f4add(qa1, ua1), f4add(ga1, A0b)));
            float4 pf0 = f4fma(cf, F1a, f4add(qf0, f4add(if0, F0a)));
            float4 pf1 = f4fma(cf, F1b, f4add(qf1, f4add(if1, F0b)));
            float4* sa = (float4*)(st_ab + srow * 128 + off8);
            sa[0] = ab0; sa[1] = ab1;
            float4* sp = (float4*)(st_pf + srow * 128 + off8);
            sp[0] = pf0; sp[1] = pf1;
        }
        if (c + 1 < NCH) LOAD_CHUNK(c + 1)
        __syncthreads();   // st visible

#pragma unroll
        for (int s = 0; s < CHK; ++s) {
            // phase A: partial matvec; lp via readlane from own wave's lc regs
            float pa = 0.f, pb = 0.f;
#pragma unroll
            for (int k = 0; k < 32; ++k) {
                const float u = __uint_as_float(
                    __builtin_amdgcn_readlane(__float_as_uint(lc), k));
                pa = fmaf(u, wA[k], pa);
                pb = fmaf(u, wB[k], pb);
            }
            *(float2*)&part[par][wv][d0] = make_float2(pa, pb);
            __syncthreads();   // the ONLY per-step barrier
            // phase B: reduce partials for owned index dd, update state
            if (l < 32) {
                const float fs = part[par][0][dd] + part[par][1][dd]
                               + part[par][2][dd] + part[par][3][dd];
                const float ab = st_ab[(s << 7) + dd];
                const float pf = st_pf[(s << 7) + dd];
                const float fg = 1.f / (1.f + __expf(-(fs + pf)));
                lc = lc * fg + ab;
                lcbuf[s] = lc;
            }
            par ^= 1;
        }
        // flush lc history for chunk c
        if (l < 32) {
#pragma unroll
            for (int s = 0; s < CHK; ++s) {
                const int t = c * CHK + s;
                if (t < Tt)
                    lc_seq[((long)t * 128 + b) * 128 + dd] = lcbuf[s];
            }
        }
    }
#undef LOAD_CHUNK
}

// ---------------- K4: parallel cosine/logit epilogue (one wave per row) ----
__global__ __launch_bounds__(256) void p5_out(
    const int* q_seq, const int* q2c, const int* q2cm,
    const float* lc_seq, const float* qdm, const float* qd10,
    const float* cnorm, const void* Eq, const void* Ec, void* out) {
    const int m = detect_mode(Eq);
    const int wv = threadIdx.x >> 6, lane = threadIdx.x & 63;
    const int r = blockIdx.x * 4 + wv;  // 6368*4 == 25472 == Tt*Bb
    const int t = r >> 7, b = r & 127;
    const int qt  = clampi(q_seq[b * Ss + t], 0, NQq - 1);
    const int qt1 = clampi(q_seq[b * Ss + t + 1], 0, NQq - 1);
    const int4 mm = ((const int4*)q2cm)[qt];
    int4 ci = ((const int4*)q2c)[qt1];
    const int c0 = clampi(ci.x, 0, NCc - 1), c1 = clampi(ci.y, 0, NCc - 1);
    const int c2 = clampi(ci.z, 0, NCc - 1), c3 = clampi(ci.w, 0, NCc - 1);
    const float la = lc_seq[(long)r * 128 + lane];
    const float lb = lc_seq[(long)r * 128 + 64 + lane];
    float nl = la * la + lb * lb;
    float d0 = la * ldf(Ec, c0 * 128 + lane, m) + lb * ldf(Ec, c0 * 128 + 64 + lane, m);
    float d1 = la * ldf(Ec, c1 * 128 + lane, m) + lb * ldf(Ec, c1 * 128 + 64 + lane, m);
    float d2 = la * ldf(Ec, c2 * 128 + lane, m) + lb * ldf(Ec, c2 * 128 + 64 + lane, m);
    float d3 = la * ldf(Ec, c3 * 128 + lane, m) + lb * ldf(Ec, c3 * 128 + 64 + lane, m);
#pragma unroll
    for (int s = 32; s >= 1; s >>= 1) {
        nl += __shfl_xor(nl, s);
        d0 += __shfl_xor(d0, s); d1 += __shfl_xor(d1, s);
        d2 += __shfl_xor(d2, s); d3 += __shfl_xor(d3, s);
    }
    if (lane == 0) {
        const float inl = 1.f / fmaxf(sqrtf(nl), 1e-8f);
        const float accv = (float)mm.x * (0.5f * d0 * inl / cnorm[c0] + 0.5f)
                         + (float)mm.y * (0.5f * d1 * inl / cnorm[c1] + 0.5f)
                         + (float)mm.z * (0.5f * d2 * inl / cnorm[c2] + 0.5f)
                         + (float)mm.w * (0.5f * d3 * inl / cnorm[c3] + 0.5f);
        const float logit = qd10[qt1] * (accv - qdm[qt]);
        stf(out, b * Ss + t, m, 1.f / (1.f + __expf(-logit)));
        if (t == 0) stf(out, b * Ss + 199, m, 0.f);
    }
}

extern "C" void kernel_launch(void* const* d_in, const int* in_sizes, int n_in,
                              void* d_out, int out_size, void* d_ws, size_t ws_size,
                              hipStream_t stream) {
    (void)in_sizes; (void)n_in; (void)out_size; (void)ws_size;
    const int* q_seq  = (const int*)d_in[0];
    const int* ha_seq = (const int*)d_in[1];
    const int* c_seq  = (const int*)d_in[2];
    const int* it_seq = (const int*)d_in[3];
    const int* ut_seq = (const int*)d_in[4];
    const int* q2c    = (const int*)d_in[5];
    const int* q2cm   = (const int*)d_in[6];
    const void* Eq   = d_in[7];
    const void* Eqd  = d_in[8];
    const void* Ec   = d_in[9];
    const void* Eit  = d_in[10];
    const void* Eut  = d_in[11];
    const void* Eha  = d_in[12];
    const void* Wf   = d_in[13];
    const void* bfu  = d_in[14];
    const void* Wa   = d_in[15];
    const void* ba   = d_in[16];
    const void* Wg   = d_in[17];
    const void* bg   = d_in[18];
    const void* L0   = d_in[19];

    // workspace layout (floats) — ~23.5 MB
    float* cnorm = (float*)d_ws;                // 512 (500 used)
    float* vA0   = cnorm + 512;                 // 128 x4
    float* vA1   = vA0 + 128;
    float* vF0   = vA1 + 128;
    float* vF1   = vF0 + 128;
    float* BabT  = vF1 + 128;                   // 16384
    float* BfgT  = BabT + 16384;                // 16384
    float* PA_ut = BfgT + 16384;                // 12800
    float* PA_ha = PA_ut + 12800;               // 1536
    float* PF_it = PA_ha + 1536;                // 12800
    float* qdm   = PF_it + 12800;               // 10016
    float* qd10  = qdm + 10016;                 // 10016
    float* PA_q  = qd10 + 10016;                // 1,280,000
    float* PF_q  = PA_q + 1280000;              // 1,280,000
    float* lc_seq= PF_q + 1280000;              // 3,260,416

    hipLaunchKernelGGL(k_prep, dim3(970), dim3(128), 0, stream,
                       Eq, Wf, Wa, Wg, bfu, ba, bg, Eut, Eha, Eit, Ec,
                       cnorm, BabT, BfgT, vA0, vA1, vF0, vF1, PA_ut, PA_ha, PF_it);
    hipLaunchKernelGGL(k_mid, dim3(2813), dim3(256), 0, stream,
                       Eq, Eqd, Ec, q2c, q2cm, BabT, BfgT, cnorm,
                       PA_q, PF_q, qdm, qd10);
    hipLaunchKernelGGL(p4_scan, dim3(Bb), dim3(256), 0, stream,
                       q_seq, ut_seq, ha_seq, it_seq, c_seq, Eq, Wg, L0,
                       PA_q, PA_ut, PA_ha, PF_q, PF_it,
                       vA0, vA1, vF0, vF1, lc_seq);
    hipLaunchKernelGGL(p5_out, dim3(Tt * Bb / 4), dim3(256), 0, stream,
                       q_seq, q2c, q2cm, lc_seq, qdm, qd10, cnorm, Eq, Ec, d_out);
}